// Round 2
// baseline (2572.108 us; speedup 1.0000x reference)
//
#include <hip/hip_runtime.h>
#include <hip/hip_bf16.h>

// Problem constants
constexpr int Bc = 2, Nc = 1024, HIDc = 2048, Hc = 32, Dc = 64, HKVc = 8, NCc = 16;

// ---------------------------------------------------------------------------
// GEMM: A fp32 [M,K] row-major x B fp32 [K,N] row-major -> C fp32 [M,N]
// 64x64 tile, BK=16, 256 threads, 4x4 micro-tile
// ---------------------------------------------------------------------------
__global__ __launch_bounds__(256) void gemm_f32(
    const float* __restrict__ A, const float* __restrict__ Bw,
    float* __restrict__ C, int M, int Nn, int K)
{
  __shared__ __align__(16) float As[16][68];
  __shared__ __align__(16) float Bs[16][68];
  const int tid = threadIdx.x;
  const int m0 = blockIdx.y * 64, n0 = blockIdx.x * 64;
  const int tx = tid & 15, ty = tid >> 4;
  float acc[4][4] = {};
  for (int k0 = 0; k0 < K; k0 += 16) {
    {
      const int r = tid >> 2, c = (tid & 3) * 4;
      const float4 av = *(const float4*)(A + (size_t)(m0 + r) * K + (k0 + c));
      As[c + 0][r] = av.x;
      As[c + 1][r] = av.y;
      As[c + 2][r] = av.z;
      As[c + 3][r] = av.w;
    }
    {
      const int r = tid >> 4, c = (tid & 15) * 4;
      const float4 bv = *(const float4*)(Bw + (size_t)(k0 + r) * Nn + (n0 + c));
      Bs[r][c + 0] = bv.x;
      Bs[r][c + 1] = bv.y;
      Bs[r][c + 2] = bv.z;
      Bs[r][c + 3] = bv.w;
    }
    __syncthreads();
#pragma unroll
    for (int kk = 0; kk < 16; ++kk) {
      float4 av = *(const float4*)&As[kk][ty * 4];
      float4 bv = *(const float4*)&Bs[kk][tx * 4];
      float a[4] = {av.x, av.y, av.z, av.w};
      float b[4] = {bv.x, bv.y, bv.z, bv.w};
#pragma unroll
      for (int i = 0; i < 4; ++i)
#pragma unroll
        for (int j = 0; j < 4; ++j) acc[i][j] += a[i] * b[j];
    }
    __syncthreads();
  }
#pragma unroll
  for (int i = 0; i < 4; ++i) {
    float* cp = C + (size_t)(m0 + ty * 4 + i) * Nn + n0 + tx * 4;
#pragma unroll
    for (int j = 0; j < 4; ++j) cp[j] = acc[i][j];
  }
}

// ---------------------------------------------------------------------------
// Per-row (64-wide) softmax of k -> kl, and log_sigmoid(k)/16 -> gl.
// One wave per row of 64. rows = B*N*HKV = 16384.
// ---------------------------------------------------------------------------
__global__ __launch_bounds__(256) void gates64_k(
    const float* __restrict__ kin, float* __restrict__ kl, float* __restrict__ gl)
{
  const int r = blockIdx.x * 4 + (threadIdx.x >> 6);
  const int lane = threadIdx.x & 63;
  const size_t idx = (size_t)r * 64 + lane;
  const float x = kin[idx];
  float m = x;
#pragma unroll
  for (int o = 32; o > 0; o >>= 1) m = fmaxf(m, __shfl_xor(m, o, 64));
  const float e = __expf(x - m);
  float s = e;
#pragma unroll
  for (int o = 32; o > 0; o >>= 1) s += __shfl_xor(s, o, 64);
  kl[idx] = e / s;
  const float ls = fminf(x, 0.f) - log1pf(__expf(-fabsf(x)));
  gl[idx] = ls * 0.0625f;
}

// ---------------------------------------------------------------------------
// Per (b,hkv,chunk): build L = (k_beta k^T) strict-lower, forward-substitute
// M u = v_beta and M w = k_beta  (M = I + L, unit lower).  256 blocks.
// ---------------------------------------------------------------------------
__global__ __launch_bounds__(256) void chunk_prep_k(
    const float* __restrict__ kl, const float* __restrict__ v,
    const float* __restrict__ gl, float* __restrict__ u_out, float* __restrict__ w_out)
{
  __shared__ float KC[64][65];  // softmaxed k; later L
  __shared__ float KB[64][65];  // k_beta; becomes w in-place
  __shared__ float VB[64][65];  // v_beta; becomes u in-place
  const int blk = blockIdx.x;  // ((b*8+hk)*16 + c)
  const int c = blk & 15, bh = blk >> 4;
  const int hk = bh & 7, b = bh >> 3;
  const int tid = threadIdx.x;
  for (int x = tid; x < 4096; x += 256) {
    const int i = x >> 6, d = x & 63;
    const size_t src = ((size_t)(b * Nc + c * 64 + i) * 8 + hk) * 64 + d;
    const float kv = kl[src], g = gl[src], vv = v[src];
    KC[i][d] = kv; KB[i][d] = kv * g; VB[i][d] = vv * g;
  }
  __syncthreads();
  float Lreg[16];
#pragma unroll
  for (int e = 0; e < 16; ++e) {
    const int x = e * 256 + tid;
    const int i = x >> 6, j = x & 63;
    float acc = 0.f;
    if (j < i) {
      for (int d = 0; d < 64; ++d) acc += KB[i][d] * KC[j][d];
    }
    Lreg[e] = acc;
  }
  __syncthreads();
#pragma unroll
  for (int e = 0; e < 16; ++e) {
    const int x = e * 256 + tid;
    KC[x >> 6][x & 63] = Lreg[e];
  }
  __syncthreads();
  if (tid < 128) {
    const int d = tid & 63;
    float (*X)[65] = (tid < 64) ? VB : KB;
    for (int i = 1; i < 64; ++i) {
      float acc = X[i][d];
      for (int j = 0; j < i; ++j) acc -= KC[i][j] * X[j][d];
      X[i][d] = acc;
    }
  }
  __syncthreads();
  for (int x = tid; x < 4096; x += 256) {
    u_out[(size_t)blk * 4096 + x] = VB[x >> 6][x & 63];
    w_out[(size_t)blk * 4096 + x] = KB[x >> 6][x & 63];
  }
}

// ---------------------------------------------------------------------------
// Serial scan over chunks per (b,hkv): S_pre[c]=S; u_p=u-wS; S+=k^T u_p.
// 16 blocks x 512 threads.
// ---------------------------------------------------------------------------
__global__ __launch_bounds__(512) void scan_k(
    const float* __restrict__ u_ps, const float* __restrict__ w_ps,
    const float* __restrict__ kl, float* __restrict__ u_p, float* __restrict__ S_pre)
{
  __shared__ float S[64][64];
  __shared__ float kw[64][64];
  __shared__ float up[64][72];
  const int blk = blockIdx.x;  // b*8 + hk
  const int hk = blk & 7, b = blk >> 3;
  const int t = threadIdx.x;
  const int row = t >> 3;        // 0..63
  const int c0 = (t & 7) * 8;    // 0..56
  for (int x = t; x < 4096; x += 512) S[x >> 6][x & 63] = 0.f;
  __syncthreads();
  for (int c = 0; c < 16; ++c) {
    const size_t cb = ((size_t)blk * 16 + c) * 4096;
    for (int x = t; x < 4096; x += 512) {
      S_pre[cb + x] = S[x >> 6][x & 63];
      kw[x >> 6][x & 63] = w_ps[cb + x];
    }
    __syncthreads();
    {
      float acc[8];
      const float* ug = u_ps + cb + row * 64 + c0;
#pragma unroll
      for (int j = 0; j < 8; ++j) acc[j] = ug[j];
      for (int e = 0; e < 64; ++e) {
        const float wv = kw[row][e];
#pragma unroll
        for (int j = 0; j < 8; ++j) acc[j] -= wv * S[e][c0 + j];
      }
      float* upg = u_p + cb + row * 64 + c0;
#pragma unroll
      for (int j = 0; j < 8; ++j) { up[row][c0 + j] = acc[j]; upg[j] = acc[j]; }
    }
    __syncthreads();
    for (int x = t; x < 4096; x += 512) {
      const int i = x >> 6, d = x & 63;
      kw[i][d] = kl[((size_t)(b * Nc + c * 64 + i) * 8 + hk) * 64 + d];
    }
    __syncthreads();
    {
      float sacc[8];
#pragma unroll
      for (int j = 0; j < 8; ++j) sacc[j] = S[row][c0 + j];
      for (int i = 0; i < 64; ++i) {
        const float kv = kw[i][row];
#pragma unroll
        for (int j = 0; j < 8; ++j) sacc[j] += kv * up[i][c0 + j];
      }
#pragma unroll
      for (int j = 0; j < 8; ++j) S[row][c0 + j] = sacc[j];
    }
    __syncthreads();
  }
}

// ---------------------------------------------------------------------------
// o_lin per (b,h,chunk): softmax(q) in-LDS, attn=(ql kc^T) tril-incl-diag,
// o = ql S_pre + attn u_p ; write 0.5*o into o_comb.  1024 blocks.
// ---------------------------------------------------------------------------
__global__ __launch_bounds__(256) void olin_k(
    const float* __restrict__ qraw, const float* __restrict__ kl,
    const float* __restrict__ upb, const float* __restrict__ S_pre,
    float* __restrict__ o_comb)
{
  __shared__ float Q[64][65];
  __shared__ __align__(16) float Bb[64][68];
  __shared__ float At[64][65];
  const int blk = blockIdx.x;  // ((b*32+h)*16 + c)
  const int c = blk & 15, bh = blk >> 4;
  const int h = bh & 31, b = bh >> 5, hk = h >> 2;
  const int tid = threadIdx.x;
  const int i = tid >> 2, d0 = (tid & 3) * 16;
  for (int x = tid; x < 4096; x += 256) {
    const int r = x >> 6, d = x & 63;
    Q[r][d] = qraw[((size_t)(b * Nc + c * 64 + r) * 32 + h) * 64 + d];
    Bb[r][d] = kl[((size_t)(b * Nc + c * 64 + r) * 8 + hk) * 64 + d];
  }
  __syncthreads();
  // softmax of own row (4 lanes/row, same wave -> in-order LDS within wave)
  {
    float mx = -1e30f;
#pragma unroll
    for (int j = 0; j < 16; ++j) mx = fmaxf(mx, Q[i][d0 + j]);
#pragma unroll
    for (int o = 1; o < 4; o <<= 1) mx = fmaxf(mx, __shfl_xor(mx, o, 64));
    float ev[16];
    float sum = 0.f;
#pragma unroll
    for (int j = 0; j < 16; ++j) { ev[j] = __expf(Q[i][d0 + j] - mx); sum += ev[j]; }
#pragma unroll
    for (int o = 1; o < 4; o <<= 1) sum += __shfl_xor(sum, o, 64);
    const float inv = 1.f / sum;
#pragma unroll
    for (int j = 0; j < 16; ++j) Q[i][d0 + j] = ev[j] * inv;
  }
  // attn tile
  {
    float a[16];
#pragma unroll
    for (int j = 0; j < 16; ++j) a[j] = 0.f;
    for (int d = 0; d < 64; ++d) {
      const float qv = Q[i][d];
#pragma unroll
      for (int j = 0; j < 16; ++j) a[j] += qv * Bb[d0 + j][d];
    }
#pragma unroll
    for (int j = 0; j < 16; ++j) At[i][d0 + j] = (d0 + j <= i) ? a[j] : 0.f;
  }
  __syncthreads();
  const size_t cb = ((size_t)(b * 8 + hk) * 16 + c) * 4096;
  for (int x = tid; x < 4096; x += 256) Bb[x >> 6][x & 63] = S_pre[cb + x];
  __syncthreads();
  float o[16];
#pragma unroll
  for (int j = 0; j < 16; ++j) o[j] = 0.f;
  for (int e = 0; e < 64; ++e) {
    const float qv = Q[i][e];
#pragma unroll
    for (int j = 0; j < 16; ++j) o[j] += qv * Bb[e][d0 + j];
  }
  __syncthreads();
  for (int x = tid; x < 4096; x += 256) Bb[x >> 6][x & 63] = upb[cb + x];
  __syncthreads();
  for (int j2 = 0; j2 < 64; ++j2) {
    const float av = At[i][j2];  // zero above diagonal -> no-op terms
#pragma unroll
    for (int j = 0; j < 16; ++j) o[j] += av * Bb[j2][d0 + j];
  }
  float* oc = o_comb + ((size_t)(b * Nc + c * 64 + i) * 32 + h) * 64 + d0;
#pragma unroll
  for (int j = 0; j < 16; ++j) oc[j] = 0.5f * o[j];
}

// ---------------------------------------------------------------------------
// Base attention pass 1: per-row max m and denom l.  1024 blocks.
// ---------------------------------------------------------------------------
__global__ __launch_bounds__(256) void base_ml_k(
    const float* __restrict__ qraw, const float* __restrict__ kraw,
    float* __restrict__ mbuf, float* __restrict__ lbuf)
{
  __shared__ float Q[64][65];
  __shared__ float Kt[64][65];
  const int blk = blockIdx.x;  // ((b*32+h)*16 + ib)
  const int ib = blk & 15, bh = blk >> 4;
  const int h = bh & 31, b = bh >> 5, hk = h >> 2;
  const int tid = threadIdx.x;
  const int i = tid >> 2, j0 = (tid & 3) * 16;
  const int ig = ib * 64 + i;
  for (int x = tid; x < 4096; x += 256) {
    const int r = x >> 6, d = x & 63;
    Q[r][d] = qraw[((size_t)(b * Nc + ib * 64 + r) * 32 + h) * 64 + d];
  }
  float m = -1e30f, l = 0.f;
  for (int jt = 0; jt <= ib; ++jt) {
    __syncthreads();
    for (int x = tid; x < 4096; x += 256) {
      const int r = x >> 6, d = x & 63;
      Kt[r][d] = kraw[((size_t)(b * Nc + jt * 64 + r) * 8 + hk) * 64 + d];
    }
    __syncthreads();
    float s[16];
#pragma unroll
    for (int j = 0; j < 16; ++j) s[j] = 0.f;
    for (int d = 0; d < 64; ++d) {
      const float qv = Q[i][d];
#pragma unroll
      for (int j = 0; j < 16; ++j) s[j] += qv * Kt[j0 + j][d];
    }
    float mt = m;
#pragma unroll
    for (int j = 0; j < 16; ++j) {
      s[j] *= 0.125f;
      if (jt * 64 + j0 + j <= ig) mt = fmaxf(mt, s[j]);
    }
    l *= __expf(m - mt);
#pragma unroll
    for (int j = 0; j < 16; ++j) {
      if (jt * 64 + j0 + j <= ig) l += __expf(s[j] - mt);
    }
    m = mt;
  }
#pragma unroll
  for (int off = 1; off < 4; off <<= 1) {
    const float mo = __shfl_xor(m, off, 64);
    const float lo = __shfl_xor(l, off, 64);
    const float mn = fmaxf(m, mo);
    l = l * __expf(m - mn) + lo * __expf(mo - mn);
    m = mn;
  }
  if ((tid & 3) == 0) {
    const size_t r = (size_t)(b * 32 + h) * 1024 + ig;
    mbuf[r] = m;
    lbuf[r] = l;
  }
}

// ---------------------------------------------------------------------------
// Base attention pass 2: p = exp(s-m)/l -> attn_out (fp32, zeros above diag),
// o_base = p @ v ; o_comb += 0.5*o_base.  1024 blocks.
// ---------------------------------------------------------------------------
__global__ __launch_bounds__(256) void base_av_k(
    const float* __restrict__ qraw, const float* __restrict__ kraw,
    const float* __restrict__ vraw, const float* __restrict__ mbuf,
    const float* __restrict__ lbuf, float* __restrict__ attn,
    float* __restrict__ o_comb)
{
  __shared__ float Q[64][65];
  __shared__ float KV[64][65];
  __shared__ float P[64][65];
  const int blk = blockIdx.x;  // ((b*32+h)*16 + ib)
  const int ib = blk & 15, bh = blk >> 4;
  const int h = bh & 31, b = bh >> 5, hk = h >> 2;
  const int tid = threadIdx.x;
  const int i = tid >> 2, c0 = (tid & 3) * 16;
  const int ig = ib * 64 + i;
  for (int x = tid; x < 4096; x += 256) {
    const int r = x >> 6, d = x & 63;
    Q[r][d] = qraw[((size_t)(b * Nc + ib * 64 + r) * 32 + h) * 64 + d];
  }
  const size_t mrow = (size_t)(b * 32 + h) * 1024 + ig;
  const float mi = mbuf[mrow];
  const float invl = 1.f / lbuf[mrow];
  float o[16];
#pragma unroll
  for (int j = 0; j < 16; ++j) o[j] = 0.f;
  float* arow = attn + ((size_t)(b * 32 + h) * 1024 + ig) * 1024;
  __syncthreads();
  for (int jt = 0; jt < 16; ++jt) {
    if (jt <= ib) {  // block-uniform condition: barriers inside are safe
      for (int x = tid; x < 4096; x += 256) {
        const int r = x >> 6, d = x & 63;
        KV[r][d] = kraw[((size_t)(b * Nc + jt * 64 + r) * 8 + hk) * 64 + d];
      }
      __syncthreads();
      float s[16];
#pragma unroll
      for (int j = 0; j < 16; ++j) s[j] = 0.f;
      for (int d = 0; d < 64; ++d) {
        const float qv = Q[i][d];
#pragma unroll
        for (int j = 0; j < 16; ++j) s[j] += qv * KV[c0 + j][d];
      }
#pragma unroll
      for (int j = 0; j < 16; ++j) {
        const int jg = jt * 64 + c0 + j;
        const float p = (jg <= ig) ? __expf(s[j] * 0.125f - mi) * invl : 0.f;
        P[i][c0 + j] = p;
        arow[jg] = p;
      }
      __syncthreads();
      for (int x = tid; x < 4096; x += 256) {
        const int r = x >> 6, d = x & 63;
        KV[r][d] = vraw[((size_t)(b * Nc + jt * 64 + r) * 8 + hk) * 64 + d];
      }
      __syncthreads();
      for (int jj = 0; jj < 64; ++jj) {
        const float pv = P[i][jj];
#pragma unroll
        for (int j = 0; j < 16; ++j) o[j] += pv * KV[jj][c0 + j];
      }
      __syncthreads();
    } else {
#pragma unroll
      for (int j = 0; j < 16; ++j) arow[jt * 64 + c0 + j] = 0.f;
    }
  }
  float* oc = o_comb + ((size_t)(b * Nc + ib * 64 + i) * 32 + h) * 64 + c0;
#pragma unroll
  for (int j = 0; j < 16; ++j) oc[j] += 0.5f * o[j];
}

// ---------------------------------------------------------------------------
extern "C" void kernel_launch(void* const* d_in, const int* in_sizes, int n_in,
                              void* d_out, int out_size, void* d_ws, size_t ws_size,
                              hipStream_t stream) {
  const float* hs = (const float*)d_in[0];
  const float* Wq = (const float*)d_in[1];
  const float* Wk = (const float*)d_in[2];
  const float* Wv = (const float*)d_in[3];
  const float* Wo = (const float*)d_in[4];
  float* out = (float*)d_out;                      // [B,N,HID]
  float* attn = out + (size_t)Bc * Nc * HIDc;      // [B,H,N,N]

  float* ws = (float*)d_ws;
  float* q_raw  = ws;                     // 4,194,304
  float* k_raw  = q_raw + 4194304;        // 1,048,576
  float* v_raw  = k_raw + 1048576;        // 1,048,576
  float* kl     = v_raw + 1048576;        // 1,048,576
  float* gl     = kl + 1048576;           // 1,048,576
  float* u_ps   = gl + 1048576;           // 2,097,152
  float* w_ps   = u_ps + 2097152;         // 2,097,152
  float* upb    = w_ps + 2097152;         // 2,097,152
  float* S_pre  = upb + 2097152;          // 2,097,152
  float* o_comb = S_pre + 2097152;        // 4,194,304
  float* mbuf   = o_comb + 4194304;       // 65,536
  float* lbuf   = mbuf + 65536;           // 65,536  -> total ~85 MB

  // Projections
  gemm_f32<<<dim3(32, 32), 256, 0, stream>>>(hs, Wq, q_raw, 2048, 2048, 2048);
  gemm_f32<<<dim3(8, 32), 256, 0, stream>>>(hs, Wk, k_raw, 2048, 512, 2048);
  gemm_f32<<<dim3(8, 32), 256, 0, stream>>>(hs, Wv, v_raw, 2048, 512, 2048);
  // Gates / feature maps for kv heads
  gates64_k<<<4096, 256, 0, stream>>>(k_raw, kl, gl);
  // Delta-rule: per-chunk triangular solves (parallel), then serial scan
  chunk_prep_k<<<256, 256, 0, stream>>>(kl, v_raw, gl, u_ps, w_ps);
  scan_k<<<16, 512, 0, stream>>>(u_ps, w_ps, kl, upb, S_pre);
  // Linear-attention output (writes o_comb = 0.5*o_lin)
  olin_k<<<1024, 256, 0, stream>>>(q_raw, kl, upb, S_pre, o_comb);
  // Base causal attention (adds 0.5*o_base, writes attn_weights)
  base_ml_k<<<1024, 256, 0, stream>>>(q_raw, k_raw, mbuf, lbuf);
  base_av_k<<<1024, 256, 0, stream>>>(q_raw, k_raw, v_raw, mbuf, lbuf, attn, o_comb);
  // Output projection
  gemm_f32<<<dim3(32, 32), 256, 0, stream>>>(o_comb, Wo, out, 2048, 2048, 2048);
}

// Round 3
// 1541.825 us; speedup vs baseline: 1.6682x; 1.6682x over previous
//
#include <hip/hip_runtime.h>
#include <hip/hip_bf16.h>

// Problem constants
constexpr int Bc = 2, Nc = 1024, HIDc = 2048, Hc = 32, Dc = 64, HKVc = 8, NCc = 16;

// ---------------------------------------------------------------------------
// GEMM: A fp32 [M,K] row-major x B fp32 [K,N] row-major -> C fp32 [M,N]
// 64x64 tile, BK=16, 256 threads, 4x4 micro-tile
// ---------------------------------------------------------------------------
__global__ __launch_bounds__(256) void gemm_f32(
    const float* __restrict__ A, const float* __restrict__ Bw,
    float* __restrict__ C, int M, int Nn, int K)
{
  __shared__ __align__(16) float As[16][68];
  __shared__ __align__(16) float Bs[16][68];
  const int tid = threadIdx.x;
  const int m0 = blockIdx.y * 64, n0 = blockIdx.x * 64;
  const int tx = tid & 15, ty = tid >> 4;
  float acc[4][4] = {};
  for (int k0 = 0; k0 < K; k0 += 16) {
    {
      const int r = tid >> 2, c = (tid & 3) * 4;
      const float4 av = *(const float4*)(A + (size_t)(m0 + r) * K + (k0 + c));
      As[c + 0][r] = av.x;
      As[c + 1][r] = av.y;
      As[c + 2][r] = av.z;
      As[c + 3][r] = av.w;
    }
    {
      const int r = tid >> 4, c = (tid & 15) * 4;
      const float4 bv = *(const float4*)(Bw + (size_t)(k0 + r) * Nn + (n0 + c));
      Bs[r][c + 0] = bv.x;
      Bs[r][c + 1] = bv.y;
      Bs[r][c + 2] = bv.z;
      Bs[r][c + 3] = bv.w;
    }
    __syncthreads();
#pragma unroll
    for (int kk = 0; kk < 16; ++kk) {
      float4 av = *(const float4*)&As[kk][ty * 4];
      float4 bv = *(const float4*)&Bs[kk][tx * 4];
      float a[4] = {av.x, av.y, av.z, av.w};
      float b[4] = {bv.x, bv.y, bv.z, bv.w};
#pragma unroll
      for (int i = 0; i < 4; ++i)
#pragma unroll
        for (int j = 0; j < 4; ++j) acc[i][j] += a[i] * b[j];
    }
    __syncthreads();
  }
#pragma unroll
  for (int i = 0; i < 4; ++i) {
    float* cp = C + (size_t)(m0 + ty * 4 + i) * Nn + n0 + tx * 4;
#pragma unroll
    for (int j = 0; j < 4; ++j) cp[j] = acc[i][j];
  }
}

// ---------------------------------------------------------------------------
// Per-row (64-wide) softmax of k -> kl, and log_sigmoid(k)/16 -> gl.
// ---------------------------------------------------------------------------
__global__ __launch_bounds__(256) void gates64_k(
    const float* __restrict__ kin, float* __restrict__ kl, float* __restrict__ gl)
{
  const int r = blockIdx.x * 4 + (threadIdx.x >> 6);
  const int lane = threadIdx.x & 63;
  const size_t idx = (size_t)r * 64 + lane;
  const float x = kin[idx];
  float m = x;
#pragma unroll
  for (int o = 32; o > 0; o >>= 1) m = fmaxf(m, __shfl_xor(m, o, 64));
  const float e = __expf(x - m);
  float s = e;
#pragma unroll
  for (int o = 32; o > 0; o >>= 1) s += __shfl_xor(s, o, 64);
  kl[idx] = e / s;
  const float ls = fminf(x, 0.f) - log1pf(__expf(-fabsf(x)));
  gl[idx] = ls * 0.0625f;
}

// ---------------------------------------------------------------------------
// Per (b,hkv,chunk): build L = (k_beta k^T) strict-lower, forward-substitute
// M u = v_beta and M w = k_beta  (M = I + L, unit lower).  256 blocks.
// ---------------------------------------------------------------------------
__global__ __launch_bounds__(256) void chunk_prep_k(
    const float* __restrict__ kl, const float* __restrict__ v,
    const float* __restrict__ gl, float* __restrict__ u_out, float* __restrict__ w_out)
{
  __shared__ float KC[64][65];
  __shared__ float KB[64][65];
  __shared__ float VB[64][65];
  const int blk = blockIdx.x;
  const int c = blk & 15, bh = blk >> 4;
  const int hk = bh & 7, b = bh >> 3;
  const int tid = threadIdx.x;
  for (int x = tid; x < 4096; x += 256) {
    const int i = x >> 6, d = x & 63;
    const size_t src = ((size_t)(b * Nc + c * 64 + i) * 8 + hk) * 64 + d;
    const float kv = kl[src], g = gl[src], vv = v[src];
    KC[i][d] = kv; KB[i][d] = kv * g; VB[i][d] = vv * g;
  }
  __syncthreads();
  float Lreg[16];
#pragma unroll
  for (int e = 0; e < 16; ++e) {
    const int x = e * 256 + tid;
    const int i = x >> 6, j = x & 63;
    float acc = 0.f;
    if (j < i) {
      for (int d = 0; d < 64; ++d) acc += KB[i][d] * KC[j][d];
    }
    Lreg[e] = acc;
  }
  __syncthreads();
#pragma unroll
  for (int e = 0; e < 16; ++e) {
    const int x = e * 256 + tid;
    KC[x >> 6][x & 63] = Lreg[e];
  }
  __syncthreads();
  if (tid < 128) {
    const int d = tid & 63;
    float (*X)[65] = (tid < 64) ? VB : KB;
    for (int i = 1; i < 64; ++i) {
      float acc = X[i][d];
      for (int j = 0; j < i; ++j) acc -= KC[i][j] * X[j][d];
      X[i][d] = acc;
    }
  }
  __syncthreads();
  for (int x = tid; x < 4096; x += 256) {
    u_out[(size_t)blk * 4096 + x] = VB[x >> 6][x & 63];
    w_out[(size_t)blk * 4096 + x] = KB[x >> 6][x & 63];
  }
}

// ---------------------------------------------------------------------------
// Serial scan over chunks per (b,hkv).  16 blocks x 512 threads.
// ---------------------------------------------------------------------------
__global__ __launch_bounds__(512) void scan_k(
    const float* __restrict__ u_ps, const float* __restrict__ w_ps,
    const float* __restrict__ kl, float* __restrict__ u_p, float* __restrict__ S_pre)
{
  __shared__ float S[64][64];
  __shared__ float kw[64][64];
  __shared__ float up[64][72];
  const int blk = blockIdx.x;
  const int hk = blk & 7, b = blk >> 3;
  const int t = threadIdx.x;
  const int row = t >> 3;
  const int c0 = (t & 7) * 8;
  for (int x = t; x < 4096; x += 512) S[x >> 6][x & 63] = 0.f;
  __syncthreads();
  for (int c = 0; c < 16; ++c) {
    const size_t cb = ((size_t)blk * 16 + c) * 4096;
    for (int x = t; x < 4096; x += 512) {
      S_pre[cb + x] = S[x >> 6][x & 63];
      kw[x >> 6][x & 63] = w_ps[cb + x];
    }
    __syncthreads();
    {
      float acc[8];
      const float* ug = u_ps + cb + row * 64 + c0;
#pragma unroll
      for (int j = 0; j < 8; ++j) acc[j] = ug[j];
      for (int e = 0; e < 64; ++e) {
        const float wv = kw[row][e];
#pragma unroll
        for (int j = 0; j < 8; ++j) acc[j] -= wv * S[e][c0 + j];
      }
      float* upg = u_p + cb + row * 64 + c0;
#pragma unroll
      for (int j = 0; j < 8; ++j) { up[row][c0 + j] = acc[j]; upg[j] = acc[j]; }
    }
    __syncthreads();
    for (int x = t; x < 4096; x += 512) {
      const int i = x >> 6, d = x & 63;
      kw[i][d] = kl[((size_t)(b * Nc + c * 64 + i) * 8 + hk) * 64 + d];
    }
    __syncthreads();
    {
      float sacc[8];
#pragma unroll
      for (int j = 0; j < 8; ++j) sacc[j] = S[row][c0 + j];
      for (int i = 0; i < 64; ++i) {
        const float kv = kw[i][row];
#pragma unroll
        for (int j = 0; j < 8; ++j) sacc[j] += kv * up[i][c0 + j];
      }
#pragma unroll
      for (int j = 0; j < 8; ++j) S[row][c0 + j] = sacc[j];
    }
    __syncthreads();
  }
}

// ---------------------------------------------------------------------------
// o_lin per (b,h,chunk).  1024 blocks.
// ---------------------------------------------------------------------------
__global__ __launch_bounds__(256) void olin_k(
    const float* __restrict__ qraw, const float* __restrict__ kl,
    const float* __restrict__ upb, const float* __restrict__ S_pre,
    float* __restrict__ o_comb)
{
  __shared__ float Q[64][65];
  __shared__ __align__(16) float Bb[64][68];
  __shared__ float At[64][65];
  const int blk = blockIdx.x;
  const int c = blk & 15, bh = blk >> 4;
  const int h = bh & 31, b = bh >> 5, hk = h >> 2;
  const int tid = threadIdx.x;
  const int i = tid >> 2, d0 = (tid & 3) * 16;
  for (int x = tid; x < 4096; x += 256) {
    const int r = x >> 6, d = x & 63;
    Q[r][d] = qraw[((size_t)(b * Nc + c * 64 + r) * 32 + h) * 64 + d];
    Bb[r][d] = kl[((size_t)(b * Nc + c * 64 + r) * 8 + hk) * 64 + d];
  }
  __syncthreads();
  {
    float mx = -1e30f;
#pragma unroll
    for (int j = 0; j < 16; ++j) mx = fmaxf(mx, Q[i][d0 + j]);
#pragma unroll
    for (int o = 1; o < 4; o <<= 1) mx = fmaxf(mx, __shfl_xor(mx, o, 64));
    float ev[16];
    float sum = 0.f;
#pragma unroll
    for (int j = 0; j < 16; ++j) { ev[j] = __expf(Q[i][d0 + j] - mx); sum += ev[j]; }
#pragma unroll
    for (int o = 1; o < 4; o <<= 1) sum += __shfl_xor(sum, o, 64);
    const float inv = 1.f / sum;
#pragma unroll
    for (int j = 0; j < 16; ++j) Q[i][d0 + j] = ev[j] * inv;
  }
  {
    float a[16];
#pragma unroll
    for (int j = 0; j < 16; ++j) a[j] = 0.f;
    for (int d = 0; d < 64; ++d) {
      const float qv = Q[i][d];
#pragma unroll
      for (int j = 0; j < 16; ++j) a[j] += qv * Bb[d0 + j][d];
    }
#pragma unroll
    for (int j = 0; j < 16; ++j) At[i][d0 + j] = (d0 + j <= i) ? a[j] : 0.f;
  }
  __syncthreads();
  const size_t cb = ((size_t)(b * 8 + hk) * 16 + c) * 4096;
  for (int x = tid; x < 4096; x += 256) Bb[x >> 6][x & 63] = S_pre[cb + x];
  __syncthreads();
  float o[16];
#pragma unroll
  for (int j = 0; j < 16; ++j) o[j] = 0.f;
  for (int e = 0; e < 64; ++e) {
    const float qv = Q[i][e];
#pragma unroll
    for (int j = 0; j < 16; ++j) o[j] += qv * Bb[e][d0 + j];
  }
  __syncthreads();
  for (int x = tid; x < 4096; x += 256) Bb[x >> 6][x & 63] = upb[cb + x];
  __syncthreads();
  for (int j2 = 0; j2 < 64; ++j2) {
    const float av = At[i][j2];
#pragma unroll
    for (int j = 0; j < 16; ++j) o[j] += av * Bb[j2][d0 + j];
  }
  float* oc = o_comb + ((size_t)(b * Nc + c * 64 + i) * 32 + h) * 64 + d0;
#pragma unroll
  for (int j = 0; j < 16; ++j) oc[j] = 0.5f * o[j];
}

// ---------------------------------------------------------------------------
// Base attention pass A: register-blocked QK^T. Writes RAW scaled scores to
// attn (-1e30 above diag, 0 for non-causal tiles) and online m,l.
// Operands staged d-major (Qt/Kt) via register 4x4 transpose -> b128 LDS ops.
// 1024 blocks x 256 threads.
// ---------------------------------------------------------------------------
__global__ __launch_bounds__(256) void score_ml_k(
    const float* __restrict__ qraw, const float* __restrict__ kraw,
    float* __restrict__ attn, float* __restrict__ mbuf, float* __restrict__ lbuf)
{
  __shared__ __align__(16) float Qt[64][68];  // [d][i]
  __shared__ __align__(16) float Kt[64][68];  // [d][j]
  const int blk = blockIdx.x;                 // ((b*32+h)*16 + ib)
  const int ib = blk & 15, bh = blk >> 4;
  const int h = bh & 31, b = bh >> 5, hk = h >> 2;
  const int tid = threadIdx.x;
  const int ty = tid >> 4, tx = tid & 15;
  const int r0 = ty * 4, c0g = tx * 4;        // staging roles: r0 = row group, c0g = col group

  // stage Qt: thread loads 4 rows x 4 d (float4 along d), writes 4 b128 along i
  {
    float4 rv[4];
#pragma unroll
    for (int rr = 0; rr < 4; ++rr)
      rv[rr] = *(const float4*)(qraw + ((size_t)(b * Nc + ib * 64 + r0 + rr) * 32 + h) * 64 + c0g);
#pragma unroll
    for (int e = 0; e < 4; ++e) {
      *(float4*)&Qt[c0g + e][r0] = make_float4(
          ((const float*)&rv[0])[e], ((const float*)&rv[1])[e],
          ((const float*)&rv[2])[e], ((const float*)&rv[3])[e]);
    }
  }

  float mrow[4], lrow[4];
#pragma unroll
  for (int r = 0; r < 4; ++r) { mrow[r] = -1e30f; lrow[r] = 0.f; }

  float* arow0 = attn + ((size_t)(b * 32 + h) * 1024 + ib * 64) * 1024;

  for (int jt = 0; jt <= ib; ++jt) {
    // stage Kt (same register-transpose trick)
    {
      float4 rv[4];
#pragma unroll
      for (int rr = 0; rr < 4; ++rr)
        rv[rr] = *(const float4*)(kraw + ((size_t)(b * Nc + jt * 64 + r0 + rr) * 8 + hk) * 64 + c0g);
#pragma unroll
      for (int e = 0; e < 4; ++e) {
        *(float4*)&Kt[c0g + e][r0] = make_float4(
            ((const float*)&rv[0])[e], ((const float*)&rv[1])[e],
            ((const float*)&rv[2])[e], ((const float*)&rv[3])[e]);
      }
    }
    __syncthreads();
    float sacc[4][4] = {};
    for (int d = 0; d < 64; ++d) {
      const float4 qa = *(const float4*)&Qt[d][ty * 4];
      const float4 kb = *(const float4*)&Kt[d][tx * 4];
      const float a[4] = {qa.x, qa.y, qa.z, qa.w};
      const float bb[4] = {kb.x, kb.y, kb.z, kb.w};
#pragma unroll
      for (int r = 0; r < 4; ++r)
#pragma unroll
        for (int c = 0; c < 4; ++c) sacc[r][c] += a[r] * bb[c];
    }
#pragma unroll
    for (int r = 0; r < 4; ++r) {
      const int ig = ib * 64 + ty * 4 + r;
      float out4[4];
      float tm = -1e30f;
#pragma unroll
      for (int c = 0; c < 4; ++c) {
        const int jg = jt * 64 + tx * 4 + c;
        const float sv = sacc[r][c] * 0.125f;
        const bool valid = (jg <= ig);
        out4[c] = valid ? sv : -1e30f;
        if (valid) tm = fmaxf(tm, sv);
      }
      const float mn = fmaxf(mrow[r], tm);
      float lsum = 0.f;
#pragma unroll
      for (int c = 0; c < 4; ++c) lsum += __expf(out4[c] - mn);  // invalid -> exp(-huge)=0
      lrow[r] = lrow[r] * __expf(mrow[r] - mn) + lsum;
      mrow[r] = mn;
      *(float4*)(arow0 + (size_t)(ty * 4 + r) * 1024 + jt * 64 + tx * 4) =
          make_float4(out4[0], out4[1], out4[2], out4[3]);
    }
    __syncthreads();
  }
  // zero-fill non-causal tiles
  {
    const float4 z = make_float4(0.f, 0.f, 0.f, 0.f);
    for (int jt2 = ib + 1; jt2 < 16; ++jt2) {
#pragma unroll
      for (int rr = 0; rr < 4; ++rr) {
        const int row = rr * 16 + ty;
        *(float4*)(arow0 + (size_t)row * 1024 + jt2 * 64 + tx * 4) = z;
      }
    }
  }
  // reduce m,l across the 16 lanes sharing a row group and write
#pragma unroll
  for (int r = 0; r < 4; ++r) {
    float m = mrow[r], l = lrow[r];
#pragma unroll
    for (int off = 1; off < 16; off <<= 1) {
      const float mo = __shfl_xor(m, off, 64);
      const float lo = __shfl_xor(l, off, 64);
      const float mn = fmaxf(m, mo);
      l = l * __expf(m - mn) + lo * __expf(mo - mn);
      m = mn;
    }
    if (tx == 0) {
      const size_t rowi = (size_t)(b * 32 + h) * 1024 + ib * 64 + ty * 4 + r;
      mbuf[rowi] = m;
      lbuf[rowi] = l;
    }
  }
}

// ---------------------------------------------------------------------------
// Base attention pass B: read raw scores, p=exp(s-m)/l, write p back to attn,
// o_base = p @ V (register-blocked, Pt staged j-major), o_comb += 0.5*o.
// 1024 blocks x 256 threads.
// ---------------------------------------------------------------------------
__global__ __launch_bounds__(256) void pv_k(
    const float* __restrict__ vraw, const float* __restrict__ mbuf,
    const float* __restrict__ lbuf, float* __restrict__ attn,
    float* __restrict__ o_comb)
{
  __shared__ __align__(16) float Pt[64][68];  // [j][i]
  __shared__ __align__(16) float Vs[64][68];  // [j][dv]
  const int blk = blockIdx.x;                 // ((b*32+h)*16 + ib)
  const int ib = blk & 15, bh = blk >> 4;
  const int h = bh & 31, b = bh >> 5, hk = h >> 2;
  const int tid = threadIdx.x;
  const int ty = tid >> 4, tx = tid & 15;
  const int i0 = ty * 4, j0 = tx * 4;

  float mi[4], il[4];
#pragma unroll
  for (int rr = 0; rr < 4; ++rr) {
    const size_t rowi = (size_t)(b * 32 + h) * 1024 + ib * 64 + i0 + rr;
    mi[rr] = mbuf[rowi];
    il[rr] = 1.f / lbuf[rowi];
  }

  float* arow0 = attn + ((size_t)(b * 32 + h) * 1024 + ib * 64) * 1024;
  float acc[4][4] = {};

  for (int jt = 0; jt <= ib; ++jt) {
    // load S tile, exp -> p, write p back, stage Pt (j-major) via reg transpose
    {
      float4 pv[4];
#pragma unroll
      for (int rr = 0; rr < 4; ++rr) {
        float* sp = arow0 + (size_t)(i0 + rr) * 1024 + jt * 64 + j0;
        const float4 s4 = *(const float4*)sp;
        const float4 p4 = make_float4(
            __expf(s4.x - mi[rr]) * il[rr], __expf(s4.y - mi[rr]) * il[rr],
            __expf(s4.z - mi[rr]) * il[rr], __expf(s4.w - mi[rr]) * il[rr]);
        *(float4*)sp = p4;
        pv[rr] = p4;
      }
#pragma unroll
      for (int e = 0; e < 4; ++e) {
        *(float4*)&Pt[j0 + e][i0] = make_float4(
            ((const float*)&pv[0])[e], ((const float*)&pv[1])[e],
            ((const float*)&pv[2])[e], ((const float*)&pv[3])[e]);
      }
    }
    // stage V tile [j][dv]
#pragma unroll
    for (int rr = 0; rr < 4; ++rr) {
      const int j = rr * 16 + ty;
      *(float4*)&Vs[j][tx * 4] =
          *(const float4*)(vraw + ((size_t)(b * Nc + jt * 64 + j) * 8 + hk) * 64 + tx * 4);
    }
    __syncthreads();
    for (int j = 0; j < 64; ++j) {
      const float4 pa = *(const float4*)&Pt[j][ty * 4];
      const float4 vb = *(const float4*)&Vs[j][tx * 4];
      const float a[4] = {pa.x, pa.y, pa.z, pa.w};
      const float bb[4] = {vb.x, vb.y, vb.z, vb.w};
#pragma unroll
      for (int r = 0; r < 4; ++r)
#pragma unroll
        for (int c = 0; c < 4; ++c) acc[r][c] += a[r] * bb[c];
    }
    __syncthreads();
  }
  // o_comb += 0.5 * acc
#pragma unroll
  for (int r = 0; r < 4; ++r) {
    float* oc = o_comb + ((size_t)(b * Nc + ib * 64 + ty * 4 + r) * 32 + h) * 64 + tx * 4;
    float4 prev = *(const float4*)oc;
    prev.x += 0.5f * acc[r][0];
    prev.y += 0.5f * acc[r][1];
    prev.z += 0.5f * acc[r][2];
    prev.w += 0.5f * acc[r][3];
    *(float4*)oc = prev;
  }
}

// ---------------------------------------------------------------------------
extern "C" void kernel_launch(void* const* d_in, const int* in_sizes, int n_in,
                              void* d_out, int out_size, void* d_ws, size_t ws_size,
                              hipStream_t stream) {
  const float* hs = (const float*)d_in[0];
  const float* Wq = (const float*)d_in[1];
  const float* Wk = (const float*)d_in[2];
  const float* Wv = (const float*)d_in[3];
  const float* Wo = (const float*)d_in[4];
  float* out = (float*)d_out;                      // [B,N,HID]
  float* attn = out + (size_t)Bc * Nc * HIDc;      // [B,H,N,N]

  float* ws = (float*)d_ws;
  float* q_raw  = ws;                     // 4,194,304
  float* k_raw  = q_raw + 4194304;        // 1,048,576
  float* v_raw  = k_raw + 1048576;        // 1,048,576
  float* kl     = v_raw + 1048576;        // 1,048,576
  float* gl     = kl + 1048576;           // 1,048,576
  float* u_ps   = gl + 1048576;           // 2,097,152
  float* w_ps   = u_ps + 2097152;         // 2,097,152
  float* upb    = w_ps + 2097152;         // 2,097,152
  float* S_pre  = upb + 2097152;          // 2,097,152
  float* o_comb = S_pre + 2097152;        // 4,194,304
  float* mbuf   = o_comb + 4194304;       // 65,536
  float* lbuf   = mbuf + 65536;           // 65,536

  // Projections
  gemm_f32<<<dim3(32, 32), 256, 0, stream>>>(hs, Wq, q_raw, 2048, 2048, 2048);
  gemm_f32<<<dim3(8, 32), 256, 0, stream>>>(hs, Wk, k_raw, 2048, 512, 2048);
  gemm_f32<<<dim3(8, 32), 256, 0, stream>>>(hs, Wv, v_raw, 2048, 512, 2048);
  // Gates / feature maps for kv heads
  gates64_k<<<4096, 256, 0, stream>>>(k_raw, kl, gl);
  // Delta-rule
  chunk_prep_k<<<256, 256, 0, stream>>>(kl, v_raw, gl, u_ps, w_ps);
  scan_k<<<16, 512, 0, stream>>>(u_ps, w_ps, kl, upb, S_pre);
  // Linear-attention output (writes o_comb = 0.5*o_lin)
  olin_k<<<1024, 256, 0, stream>>>(q_raw, kl, upb, S_pre, o_comb);
  // Base causal attention: scores once (raw) + m,l; then p + PV
  score_ml_k<<<1024, 256, 0, stream>>>(q_raw, k_raw, attn, mbuf, lbuf);
  pv_k<<<1024, 256, 0, stream>>>(v_raw, mbuf, lbuf, attn, o_comb);
  // Output projection
  gemm_f32<<<dim3(32, 32), 256, 0, stream>>>(o_comb, Wo, out, 2048, 2048, 2048);
}

// Round 4
// 1069.219 us; speedup vs baseline: 2.4056x; 1.4420x over previous
//
#include <hip/hip_runtime.h>
#include <hip/hip_bf16.h>

// Problem constants
constexpr int Bc = 2, Nc = 1024, HIDc = 2048, Hc = 32, Dc = 64, HKVc = 8, NCc = 16;

typedef unsigned short bfu;  // raw bf16 bits
typedef __attribute__((ext_vector_type(8))) short frag_ab;  // 8 bf16 (4 VGPRs)
typedef __attribute__((ext_vector_type(4))) float frag_cd;  // 4 fp32 acc

__device__ __forceinline__ bfu f2bf(float f) {
  unsigned int u = __float_as_uint(f);
  unsigned int r = u + 0x7fffu + ((u >> 16) & 1u);  // RNE
  return (bfu)(r >> 16);
}

// ---------------------------------------------------------------------------
// Flat cast fp32 -> bf16 (4 elements/thread)
// ---------------------------------------------------------------------------
__global__ __launch_bounds__(256) void cast_bf16_k(
    const float* __restrict__ in, bfu* __restrict__ out)
{
  const size_t i = ((size_t)blockIdx.x * 256 + threadIdx.x) * 4;
  const float4 v = *(const float4*)(in + i);
  ushort4 p;
  p.x = f2bf(v.x); p.y = f2bf(v.y); p.z = f2bf(v.z); p.w = f2bf(v.w);
  *(ushort4*)(out + i) = p;
}

// ---------------------------------------------------------------------------
// Transpose + cast: W fp32 [K][N] -> WT bf16 [N][K].  32x32 tiles, 256 thr.
// ---------------------------------------------------------------------------
__global__ __launch_bounds__(256) void transpose_cast_k(
    const float* __restrict__ W, bfu* __restrict__ WT, int K, int N)
{
  __shared__ float t[32][33];
  const int bn = blockIdx.x * 32, bk = blockIdx.y * 32;
  const int x = threadIdx.x & 31, y = threadIdx.x >> 5;  // 32x8
#pragma unroll
  for (int i = 0; i < 32; i += 8)
    t[y + i][x] = W[(size_t)(bk + y + i) * N + bn + x];
  __syncthreads();
#pragma unroll
  for (int i = 0; i < 32; i += 8)
    WT[(size_t)(bn + y + i) * K + bk + x] = f2bf(t[x][y + i]);
}

// ---------------------------------------------------------------------------
// MFMA GEMM: A bf16 [M][K] x BT bf16 [N][K] -> C fp32 [M][N].
// 128x128 tile, BK=32, 256 threads (4 waves, 2x2), 4x4 mfma_f32_16x16x32_bf16
// per wave. LDS rows padded to 40 bf16 (80 B) -> b128-aligned frag reads.
// ---------------------------------------------------------------------------
__global__ __launch_bounds__(256) void gemm_mfma_bt(
    const bfu* __restrict__ A, const bfu* __restrict__ BT,
    float* __restrict__ C, int M, int Nn, int K)
{
  constexpr int LDK = 40;
  __shared__ __align__(16) bfu As[128 * LDK];
  __shared__ __align__(16) bfu Bs[128 * LDK];
  const int tid = threadIdx.x;
  const int m0 = blockIdx.y * 128, n0 = blockIdx.x * 128;
  const int wave = tid >> 6, lane = tid & 63;
  const int wm = (wave >> 1) * 64, wn = (wave & 1) * 64;
  const int fm = lane & 15, quad = lane >> 4;
  const int sr = tid >> 2, skc = (tid & 3) * 8;  // staging: row, k-chunk

  frag_cd acc[4][4];
#pragma unroll
  for (int i = 0; i < 4; ++i)
#pragma unroll
    for (int j = 0; j < 4; ++j) acc[i][j] = (frag_cd){0.f, 0.f, 0.f, 0.f};

  for (int k0 = 0; k0 < K; k0 += 32) {
    *(uint4*)&As[(size_t)sr * LDK + skc] =
        *(const uint4*)(A + (size_t)(m0 + sr) * K + k0 + skc);
    *(uint4*)&As[(size_t)(sr + 64) * LDK + skc] =
        *(const uint4*)(A + (size_t)(m0 + sr + 64) * K + k0 + skc);
    *(uint4*)&Bs[(size_t)sr * LDK + skc] =
        *(const uint4*)(BT + (size_t)(n0 + sr) * K + k0 + skc);
    *(uint4*)&Bs[(size_t)(sr + 64) * LDK + skc] =
        *(const uint4*)(BT + (size_t)(n0 + sr + 64) * K + k0 + skc);
    __syncthreads();
    frag_ab a[4], b[4];
#pragma unroll
    for (int im = 0; im < 4; ++im)
      a[im] = *(const frag_ab*)&As[(size_t)(wm + im * 16 + fm) * LDK + quad * 8];
#pragma unroll
    for (int in = 0; in < 4; ++in)
      b[in] = *(const frag_ab*)&Bs[(size_t)(wn + in * 16 + fm) * LDK + quad * 8];
#pragma unroll
    for (int im = 0; im < 4; ++im)
#pragma unroll
      for (int in = 0; in < 4; ++in)
        acc[im][in] = __builtin_amdgcn_mfma_f32_16x16x32_bf16(
            a[im], b[in], acc[im][in], 0, 0, 0);
    __syncthreads();
  }
  // C/D layout: col = lane&15, row = quad*4 + reg   [m89/m91 verified]
#pragma unroll
  for (int im = 0; im < 4; ++im)
#pragma unroll
    for (int in = 0; in < 4; ++in) {
      const int n = n0 + wn + in * 16 + fm;
#pragma unroll
      for (int r = 0; r < 4; ++r) {
        const int m = m0 + wm + im * 16 + quad * 4 + r;
        C[(size_t)m * Nn + n] = acc[im][in][r];
      }
    }
}

// ---------------------------------------------------------------------------
// Per-row (64-wide) softmax of k -> kl, and log_sigmoid(k)/16 -> gl.
// ---------------------------------------------------------------------------
__global__ __launch_bounds__(256) void gates64_k(
    const float* __restrict__ kin, float* __restrict__ kl, float* __restrict__ gl)
{
  const int r = blockIdx.x * 4 + (threadIdx.x >> 6);
  const int lane = threadIdx.x & 63;
  const size_t idx = (size_t)r * 64 + lane;
  const float x = kin[idx];
  float m = x;
#pragma unroll
  for (int o = 32; o > 0; o >>= 1) m = fmaxf(m, __shfl_xor(m, o, 64));
  const float e = __expf(x - m);
  float s = e;
#pragma unroll
  for (int o = 32; o > 0; o >>= 1) s += __shfl_xor(s, o, 64);
  kl[idx] = e / s;
  const float ls = fminf(x, 0.f) - log1pf(__expf(-fabsf(x)));
  gl[idx] = ls * 0.0625f;
}

// ---------------------------------------------------------------------------
// Per (b,hkv,chunk): build L = (k_beta k^T) strict-lower, forward-substitute
// M u = v_beta and M w = k_beta  (M = I + L, unit lower).  256 blocks.
// ---------------------------------------------------------------------------
__global__ __launch_bounds__(256) void chunk_prep_k(
    const float* __restrict__ kl, const float* __restrict__ v,
    const float* __restrict__ gl, float* __restrict__ u_out, float* __restrict__ w_out)
{
  __shared__ float KC[64][65];
  __shared__ float KB[64][65];
  __shared__ float VB[64][65];
  const int blk = blockIdx.x;
  const int c = blk & 15, bh = blk >> 4;
  const int hk = bh & 7, b = bh >> 3;
  const int tid = threadIdx.x;
  for (int x = tid; x < 4096; x += 256) {
    const int i = x >> 6, d = x & 63;
    const size_t src = ((size_t)(b * Nc + c * 64 + i) * 8 + hk) * 64 + d;
    const float kv = kl[src], g = gl[src], vv = v[src];
    KC[i][d] = kv; KB[i][d] = kv * g; VB[i][d] = vv * g;
  }
  __syncthreads();
  float Lreg[16];
#pragma unroll
  for (int e = 0; e < 16; ++e) {
    const int x = e * 256 + tid;
    const int i = x >> 6, j = x & 63;
    float acc = 0.f;
    if (j < i) {
      for (int d = 0; d < 64; ++d) acc += KB[i][d] * KC[j][d];
    }
    Lreg[e] = acc;
  }
  __syncthreads();
#pragma unroll
  for (int e = 0; e < 16; ++e) {
    const int x = e * 256 + tid;
    KC[x >> 6][x & 63] = Lreg[e];
  }
  __syncthreads();
  if (tid < 128) {
    const int d = tid & 63;
    float (*X)[65] = (tid < 64) ? VB : KB;
    for (int i = 1; i < 64; ++i) {
      float acc = X[i][d];
      for (int j = 0; j < i; ++j) acc -= KC[i][j] * X[j][d];
      X[i][d] = acc;
    }
  }
  __syncthreads();
  for (int x = tid; x < 4096; x += 256) {
    u_out[(size_t)blk * 4096 + x] = VB[x >> 6][x & 63];
    w_out[(size_t)blk * 4096 + x] = KB[x >> 6][x & 63];
  }
}

// ---------------------------------------------------------------------------
// Serial scan over chunks per (b,hkv).  16 blocks x 512 threads.
// ---------------------------------------------------------------------------
__global__ __launch_bounds__(512) void scan_k(
    const float* __restrict__ u_ps, const float* __restrict__ w_ps,
    const float* __restrict__ kl, float* __restrict__ u_p, float* __restrict__ S_pre)
{
  __shared__ float S[64][64];
  __shared__ float kw[64][64];
  __shared__ float up[64][72];
  const int blk = blockIdx.x;
  const int hk = blk & 7, b = blk >> 3;
  const int t = threadIdx.x;
  const int row = t >> 3;
  const int c0 = (t & 7) * 8;
  for (int x = t; x < 4096; x += 512) S[x >> 6][x & 63] = 0.f;
  __syncthreads();
  for (int c = 0; c < 16; ++c) {
    const size_t cb = ((size_t)blk * 16 + c) * 4096;
    for (int x = t; x < 4096; x += 512) {
      S_pre[cb + x] = S[x >> 6][x & 63];
      kw[x >> 6][x & 63] = w_ps[cb + x];
    }
    __syncthreads();
    {
      float acc[8];
      const float* ug = u_ps + cb + row * 64 + c0;
#pragma unroll
      for (int j = 0; j < 8; ++j) acc[j] = ug[j];
      for (int e = 0; e < 64; ++e) {
        const float wv = kw[row][e];
#pragma unroll
        for (int j = 0; j < 8; ++j) acc[j] -= wv * S[e][c0 + j];
      }
      float* upg = u_p + cb + row * 64 + c0;
#pragma unroll
      for (int j = 0; j < 8; ++j) { up[row][c0 + j] = acc[j]; upg[j] = acc[j]; }
    }
    __syncthreads();
    for (int x = t; x < 4096; x += 512) {
      const int i = x >> 6, d = x & 63;
      kw[i][d] = kl[((size_t)(b * Nc + c * 64 + i) * 8 + hk) * 64 + d];
    }
    __syncthreads();
    {
      float sacc[8];
#pragma unroll
      for (int j = 0; j < 8; ++j) sacc[j] = S[row][c0 + j];
      for (int i = 0; i < 64; ++i) {
        const float kv = kw[i][row];
#pragma unroll
        for (int j = 0; j < 8; ++j) sacc[j] += kv * up[i][c0 + j];
      }
#pragma unroll
      for (int j = 0; j < 8; ++j) S[row][c0 + j] = sacc[j];
    }
    __syncthreads();
  }
}

// ---------------------------------------------------------------------------
// o_lin per (b,h,chunk).  1024 blocks.
// ---------------------------------------------------------------------------
__global__ __launch_bounds__(256) void olin_k(
    const float* __restrict__ qraw, const float* __restrict__ kl,
    const float* __restrict__ upb, const float* __restrict__ S_pre,
    float* __restrict__ o_comb)
{
  __shared__ float Q[64][65];
  __shared__ __align__(16) float Bb[64][68];
  __shared__ float At[64][65];
  const int blk = blockIdx.x;
  const int c = blk & 15, bh = blk >> 4;
  const int h = bh & 31, b = bh >> 5, hk = h >> 2;
  const int tid = threadIdx.x;
  const int i = tid >> 2, d0 = (tid & 3) * 16;
  for (int x = tid; x < 4096; x += 256) {
    const int r = x >> 6, d = x & 63;
    Q[r][d] = qraw[((size_t)(b * Nc + c * 64 + r) * 32 + h) * 64 + d];
    Bb[r][d] = kl[((size_t)(b * Nc + c * 64 + r) * 8 + hk) * 64 + d];
  }
  __syncthreads();
  {
    float mx = -1e30f;
#pragma unroll
    for (int j = 0; j < 16; ++j) mx = fmaxf(mx, Q[i][d0 + j]);
#pragma unroll
    for (int o = 1; o < 4; o <<= 1) mx = fmaxf(mx, __shfl_xor(mx, o, 64));
    float ev[16];
    float sum = 0.f;
#pragma unroll
    for (int j = 0; j < 16; ++j) { ev[j] = __expf(Q[i][d0 + j] - mx); sum += ev[j]; }
#pragma unroll
    for (int o = 1; o < 4; o <<= 1) sum += __shfl_xor(sum, o, 64);
    const float inv = 1.f / sum;
#pragma unroll
    for (int j = 0; j < 16; ++j) Q[i][d0 + j] = ev[j] * inv;
  }
  {
    float a[16];
#pragma unroll
    for (int j = 0; j < 16; ++j) a[j] = 0.f;
    for (int d = 0; d < 64; ++d) {
      const float qv = Q[i][d];
#pragma unroll
      for (int j = 0; j < 16; ++j) a[j] += qv * Bb[d0 + j][d];
    }
#pragma unroll
    for (int j = 0; j < 16; ++j) At[i][d0 + j] = (d0 + j <= i) ? a[j] : 0.f;
  }
  __syncthreads();
  const size_t cb = ((size_t)(b * 8 + hk) * 16 + c) * 4096;
  for (int x = tid; x < 4096; x += 256) Bb[x >> 6][x & 63] = S_pre[cb + x];
  __syncthreads();
  float o[16];
#pragma unroll
  for (int j = 0; j < 16; ++j) o[j] = 0.f;
  for (int e = 0; e < 64; ++e) {
    const float qv = Q[i][e];
#pragma unroll
    for (int j = 0; j < 16; ++j) o[j] += qv * Bb[e][d0 + j];
  }
  __syncthreads();
  for (int x = tid; x < 4096; x += 256) Bb[x >> 6][x & 63] = upb[cb + x];
  __syncthreads();
  for (int j2 = 0; j2 < 64; ++j2) {
    const float av = At[i][j2];
#pragma unroll
    for (int j = 0; j < 16; ++j) o[j] += av * Bb[j2][d0 + j];
  }
  float* oc = o_comb + ((size_t)(b * Nc + c * 64 + i) * 32 + h) * 64 + d0;
#pragma unroll
  for (int j = 0; j < 16; ++j) oc[j] = 0.5f * o[j];
}

// ---------------------------------------------------------------------------
// Base attention pass A: register-blocked QK^T -> raw scores + online m,l.
// ---------------------------------------------------------------------------
__global__ __launch_bounds__(256) void score_ml_k(
    const float* __restrict__ qraw, const float* __restrict__ kraw,
    float* __restrict__ attn, float* __restrict__ mbuf, float* __restrict__ lbuf)
{
  __shared__ __align__(16) float Qt[64][68];
  __shared__ __align__(16) float Kt[64][68];
  const int blk = blockIdx.x;
  const int ib = blk & 15, bh = blk >> 4;
  const int h = bh & 31, b = bh >> 5, hk = h >> 2;
  const int tid = threadIdx.x;
  const int ty = tid >> 4, tx = tid & 15;
  const int r0 = ty * 4, c0g = tx * 4;
  {
    float4 rv[4];
#pragma unroll
    for (int rr = 0; rr < 4; ++rr)
      rv[rr] = *(const float4*)(qraw + ((size_t)(b * Nc + ib * 64 + r0 + rr) * 32 + h) * 64 + c0g);
#pragma unroll
    for (int e = 0; e < 4; ++e) {
      *(float4*)&Qt[c0g + e][r0] = make_float4(
          ((const float*)&rv[0])[e], ((const float*)&rv[1])[e],
          ((const float*)&rv[2])[e], ((const float*)&rv[3])[e]);
    }
  }
  float mrow[4], lrow[4];
#pragma unroll
  for (int r = 0; r < 4; ++r) { mrow[r] = -1e30f; lrow[r] = 0.f; }
  float* arow0 = attn + ((size_t)(b * 32 + h) * 1024 + ib * 64) * 1024;
  for (int jt = 0; jt <= ib; ++jt) {
    {
      float4 rv[4];
#pragma unroll
      for (int rr = 0; rr < 4; ++rr)
        rv[rr] = *(const float4*)(kraw + ((size_t)(b * Nc + jt * 64 + r0 + rr) * 8 + hk) * 64 + c0g);
#pragma unroll
      for (int e = 0; e < 4; ++e) {
        *(float4*)&Kt[c0g + e][r0] = make_float4(
            ((const float*)&rv[0])[e], ((const float*)&rv[1])[e],
            ((const float*)&rv[2])[e], ((const float*)&rv[3])[e]);
      }
    }
    __syncthreads();
    float sacc[4][4] = {};
    for (int d = 0; d < 64; ++d) {
      const float4 qa = *(const float4*)&Qt[d][ty * 4];
      const float4 kb = *(const float4*)&Kt[d][tx * 4];
      const float a[4] = {qa.x, qa.y, qa.z, qa.w};
      const float bb[4] = {kb.x, kb.y, kb.z, kb.w};
#pragma unroll
      for (int r = 0; r < 4; ++r)
#pragma unroll
        for (int c = 0; c < 4; ++c) sacc[r][c] += a[r] * bb[c];
    }
#pragma unroll
    for (int r = 0; r < 4; ++r) {
      const int ig = ib * 64 + ty * 4 + r;
      float out4[4];
      float tm = -1e30f;
#pragma unroll
      for (int c = 0; c < 4; ++c) {
        const int jg = jt * 64 + tx * 4 + c;
        const float sv = sacc[r][c] * 0.125f;
        const bool valid = (jg <= ig);
        out4[c] = valid ? sv : -1e30f;
        if (valid) tm = fmaxf(tm, sv);
      }
      const float mn = fmaxf(mrow[r], tm);
      float lsum = 0.f;
#pragma unroll
      for (int c = 0; c < 4; ++c) lsum += __expf(out4[c] - mn);
      lrow[r] = lrow[r] * __expf(mrow[r] - mn) + lsum;
      mrow[r] = mn;
      *(float4*)(arow0 + (size_t)(ty * 4 + r) * 1024 + jt * 64 + tx * 4) =
          make_float4(out4[0], out4[1], out4[2], out4[3]);
    }
    __syncthreads();
  }
  {
    const float4 z = make_float4(0.f, 0.f, 0.f, 0.f);
    for (int jt2 = ib + 1; jt2 < 16; ++jt2) {
#pragma unroll
      for (int rr = 0; rr < 4; ++rr) {
        const int row = rr * 16 + ty;
        *(float4*)(arow0 + (size_t)row * 1024 + jt2 * 64 + tx * 4) = z;
      }
    }
  }
#pragma unroll
  for (int r = 0; r < 4; ++r) {
    float m = mrow[r], l = lrow[r];
#pragma unroll
    for (int off = 1; off < 16; off <<= 1) {
      const float mo = __shfl_xor(m, off, 64);
      const float lo = __shfl_xor(l, off, 64);
      const float mn = fmaxf(m, mo);
      l = l * __expf(m - mn) + lo * __expf(mo - mn);
      m = mn;
    }
    if (tx == 0) {
      const size_t rowi = (size_t)(b * 32 + h) * 1024 + ib * 64 + ty * 4 + r;
      mbuf[rowi] = m;
      lbuf[rowi] = l;
    }
  }
}

// ---------------------------------------------------------------------------
// Base attention pass B: p=exp(s-m)/l -> attn, o_base = p @ V, o_comb += 0.5*o.
// ---------------------------------------------------------------------------
__global__ __launch_bounds__(256) void pv_k(
    const float* __restrict__ vraw, const float* __restrict__ mbuf,
    const float* __restrict__ lbuf, float* __restrict__ attn,
    float* __restrict__ o_comb)
{
  __shared__ __align__(16) float Pt[64][68];
  __shared__ __align__(16) float Vs[64][68];
  const int blk = blockIdx.x;
  const int ib = blk & 15, bh = blk >> 4;
  const int h = bh & 31, b = bh >> 5, hk = h >> 2;
  const int tid = threadIdx.x;
  const int ty = tid >> 4, tx = tid & 15;
  const int i0 = ty * 4, j0 = tx * 4;
  float mi[4], il[4];
#pragma unroll
  for (int rr = 0; rr < 4; ++rr) {
    const size_t rowi = (size_t)(b * 32 + h) * 1024 + ib * 64 + i0 + rr;
    mi[rr] = mbuf[rowi];
    il[rr] = 1.f / lbuf[rowi];
  }
  float* arow0 = attn + ((size_t)(b * 32 + h) * 1024 + ib * 64) * 1024;
  float acc[4][4] = {};
  for (int jt = 0; jt <= ib; ++jt) {
    {
      float4 pv[4];
#pragma unroll
      for (int rr = 0; rr < 4; ++rr) {
        float* sp = arow0 + (size_t)(i0 + rr) * 1024 + jt * 64 + j0;
        const float4 s4 = *(const float4*)sp;
        const float4 p4 = make_float4(
            __expf(s4.x - mi[rr]) * il[rr], __expf(s4.y - mi[rr]) * il[rr],
            __expf(s4.z - mi[rr]) * il[rr], __expf(s4.w - mi[rr]) * il[rr]);
        *(float4*)sp = p4;
        pv[rr] = p4;
      }
#pragma unroll
      for (int e = 0; e < 4; ++e) {
        *(float4*)&Pt[j0 + e][i0] = make_float4(
            ((const float*)&pv[0])[e], ((const float*)&pv[1])[e],
            ((const float*)&pv[2])[e], ((const float*)&pv[3])[e]);
      }
    }
#pragma unroll
    for (int rr = 0; rr < 4; ++rr) {
      const int j = rr * 16 + ty;
      *(float4*)&Vs[j][tx * 4] =
          *(const float4*)(vraw + ((size_t)(b * Nc + jt * 64 + j) * 8 + hk) * 64 + tx * 4);
    }
    __syncthreads();
    for (int j = 0; j < 64; ++j) {
      const float4 pa = *(const float4*)&Pt[j][ty * 4];
      const float4 vb = *(const float4*)&Vs[j][tx * 4];
      const float a[4] = {pa.x, pa.y, pa.z, pa.w};
      const float bb[4] = {vb.x, vb.y, vb.z, vb.w};
#pragma unroll
      for (int r = 0; r < 4; ++r)
#pragma unroll
        for (int c = 0; c < 4; ++c) acc[r][c] += a[r] * bb[c];
    }
    __syncthreads();
  }
#pragma unroll
  for (int r = 0; r < 4; ++r) {
    float* oc = o_comb + ((size_t)(b * Nc + ib * 64 + ty * 4 + r) * 32 + h) * 64 + tx * 4;
    float4 prev = *(const float4*)oc;
    prev.x += 0.5f * acc[r][0];
    prev.y += 0.5f * acc[r][1];
    prev.z += 0.5f * acc[r][2];
    prev.w += 0.5f * acc[r][3];
    *(float4*)oc = prev;
  }
}

// ---------------------------------------------------------------------------
extern "C" void kernel_launch(void* const* d_in, const int* in_sizes, int n_in,
                              void* d_out, int out_size, void* d_ws, size_t ws_size,
                              hipStream_t stream) {
  const float* hs = (const float*)d_in[0];
  const float* Wq = (const float*)d_in[1];
  const float* Wk = (const float*)d_in[2];
  const float* Wv = (const float*)d_in[3];
  const float* Wo = (const float*)d_in[4];
  float* out = (float*)d_out;                      // [B,N,HID]
  float* attn = out + (size_t)Bc * Nc * HIDc;      // [B,H,N,N]

  float* ws = (float*)d_ws;
  float* q_raw  = ws;                     // 4,194,304 f32
  float* k_raw  = q_raw + 4194304;        // 1,048,576
  float* v_raw  = k_raw + 1048576;        // 1,048,576
  float* kl     = v_raw + 1048576;        // 1,048,576
  float* gl     = kl + 1048576;           // 1,048,576
  float* u_ps   = gl + 1048576;           // 2,097,152
  float* w_ps   = u_ps + 2097152;         // 2,097,152
  float* upb    = w_ps + 2097152;         // 2,097,152
  float* S_pre  = upb + 2097152;          // 2,097,152
  float* o_comb = S_pre + 2097152;        // 4,194,304
  float* mbuf   = o_comb + 4194304;       // 65,536
  float* lbuf   = mbuf + 65536;           // 65,536
  // bf16 region (raw ushort), after the fp32 region
  bfu* bstart = (bfu*)(lbuf + 65536);
  bfu* hs_bf  = bstart;                   // 4,194,304 bf16
  bfu* WqT    = hs_bf + 4194304;          // 4,194,304
  bfu* WkT    = WqT + 4194304;            // 1,048,576
  bfu* WvT    = WkT + 1048576;            // 1,048,576
  bfu* WoT    = WvT + 1048576;            // 4,194,304
  bfu* oc_bf  = WoT + 4194304;            // 4,194,304   (total ws ~ 124 MB)

  // Casts / weight transposes (bf16 B^T layout for MFMA GEMM)
  cast_bf16_k<<<4096, 256, 0, stream>>>(hs, hs_bf);
  transpose_cast_k<<<dim3(64, 64), 256, 0, stream>>>(Wq, WqT, 2048, 2048);
  transpose_cast_k<<<dim3(16, 64), 256, 0, stream>>>(Wk, WkT, 2048, 512);
  transpose_cast_k<<<dim3(16, 64), 256, 0, stream>>>(Wv, WvT, 2048, 512);
  transpose_cast_k<<<dim3(64, 64), 256, 0, stream>>>(Wo, WoT, 2048, 2048);
  // Projections (bf16 MFMA, fp32 out)
  gemm_mfma_bt<<<dim3(16, 16), 256, 0, stream>>>(hs_bf, WqT, q_raw, 2048, 2048, 2048);
  gemm_mfma_bt<<<dim3(4, 16), 256, 0, stream>>>(hs_bf, WkT, k_raw, 2048, 512, 2048);
  gemm_mfma_bt<<<dim3(4, 16), 256, 0, stream>>>(hs_bf, WvT, v_raw, 2048, 512, 2048);
  // Gates / feature maps for kv heads
  gates64_k<<<4096, 256, 0, stream>>>(k_raw, kl, gl);
  // Delta-rule
  chunk_prep_k<<<256, 256, 0, stream>>>(kl, v_raw, gl, u_ps, w_ps);
  scan_k<<<16, 512, 0, stream>>>(u_ps, w_ps, kl, upb, S_pre);
  // Linear-attention output (writes o_comb = 0.5*o_lin)
  olin_k<<<1024, 256, 0, stream>>>(q_raw, kl, upb, S_pre, o_comb);
  // Base causal attention: scores once (raw) + m,l; then p + PV
  score_ml_k<<<1024, 256, 0, stream>>>(q_raw, k_raw, attn, mbuf, lbuf);
  pv_k<<<1024, 256, 0, stream>>>(v_raw, mbuf, lbuf, attn, o_comb);
  // Output projection (bf16 MFMA, writes fp32 out directly)
  cast_bf16_k<<<4096, 256, 0, stream>>>(o_comb, oc_bf);
  gemm_mfma_bt<<<dim3(16, 16), 256, 0, stream>>>(oc_bf, WoT, out, 2048, 2048, 2048);
}

// Round 5
// 857.974 us; speedup vs baseline: 2.9979x; 1.2462x over previous
//
#include <hip/hip_runtime.h>
#include <hip/hip_bf16.h>

// Problem constants
constexpr int Bc = 2, Nc = 1024, HIDc = 2048, Hc = 32, Dc = 64, HKVc = 8, NCc = 16;

typedef unsigned short bfu;  // raw bf16 bits
typedef __attribute__((ext_vector_type(8))) short frag_ab;  // 8 bf16 (4 VGPRs)
typedef __attribute__((ext_vector_type(4))) float frag_cd;  // 4 fp32 acc

__device__ __forceinline__ bfu f2bf(float f) {
  unsigned int u = __float_as_uint(f);
  unsigned int r = u + 0x7fffu + ((u >> 16) & 1u);  // RNE
  return (bfu)(r >> 16);
}
__device__ __forceinline__ ushort4 pack4(float4 v) {
  ushort4 r; r.x = f2bf(v.x); r.y = f2bf(v.y); r.z = f2bf(v.z); r.w = f2bf(v.w);
  return r;
}

// ---------------------------------------------------------------------------
// Flat cast fp32 -> bf16 (4 elements/thread)
// ---------------------------------------------------------------------------
__global__ __launch_bounds__(256) void cast_bf16_k(
    const float* __restrict__ in, bfu* __restrict__ out)
{
  const size_t i = ((size_t)blockIdx.x * 256 + threadIdx.x) * 4;
  *(ushort4*)(out + i) = pack4(*(const float4*)(in + i));
}

// ---------------------------------------------------------------------------
// Transpose + cast: W fp32 [K][N] -> WT bf16 [N][K].  32x32 tiles, 256 thr.
// ---------------------------------------------------------------------------
__global__ __launch_bounds__(256) void transpose_cast_k(
    const float* __restrict__ W, bfu* __restrict__ WT, int K, int N)
{
  __shared__ float t[32][33];
  const int bn = blockIdx.x * 32, bk = blockIdx.y * 32;
  const int x = threadIdx.x & 31, y = threadIdx.x >> 5;  // 32x8
#pragma unroll
  for (int i = 0; i < 32; i += 8)
    t[y + i][x] = W[(size_t)(bk + y + i) * N + bn + x];
  __syncthreads();
#pragma unroll
  for (int i = 0; i < 32; i += 8)
    WT[(size_t)(bn + y + i) * K + bk + x] = f2bf(t[x][y + i]);
}

// ---------------------------------------------------------------------------
// MFMA GEMM: A bf16 [M][K] x BT bf16 [N][K] -> C fp32 [M][N].
// 128x128 tile, BK=32, 256 threads (4 waves, 2x2), 4x4 mfma_f32_16x16x32_bf16.
// ---------------------------------------------------------------------------
__global__ __launch_bounds__(256) void gemm_mfma_bt(
    const bfu* __restrict__ A, const bfu* __restrict__ BT,
    float* __restrict__ C, int M, int Nn, int K)
{
  constexpr int LDK = 40;
  __shared__ __align__(16) bfu As[128 * LDK];
  __shared__ __align__(16) bfu Bs[128 * LDK];
  const int tid = threadIdx.x;
  const int m0 = blockIdx.y * 128, n0 = blockIdx.x * 128;
  const int wave = tid >> 6, lane = tid & 63;
  const int wm = (wave >> 1) * 64, wn = (wave & 1) * 64;
  const int fm = lane & 15, quad = lane >> 4;
  const int sr = tid >> 2, skc = (tid & 3) * 8;

  frag_cd acc[4][4];
#pragma unroll
  for (int i = 0; i < 4; ++i)
#pragma unroll
    for (int j = 0; j < 4; ++j) acc[i][j] = (frag_cd){0.f, 0.f, 0.f, 0.f};

  for (int k0 = 0; k0 < K; k0 += 32) {
    *(uint4*)&As[(size_t)sr * LDK + skc] =
        *(const uint4*)(A + (size_t)(m0 + sr) * K + k0 + skc);
    *(uint4*)&As[(size_t)(sr + 64) * LDK + skc] =
        *(const uint4*)(A + (size_t)(m0 + sr + 64) * K + k0 + skc);
    *(uint4*)&Bs[(size_t)sr * LDK + skc] =
        *(const uint4*)(BT + (size_t)(n0 + sr) * K + k0 + skc);
    *(uint4*)&Bs[(size_t)(sr + 64) * LDK + skc] =
        *(const uint4*)(BT + (size_t)(n0 + sr + 64) * K + k0 + skc);
    __syncthreads();
    frag_ab a[4], b[4];
#pragma unroll
    for (int im = 0; im < 4; ++im)
      a[im] = *(const frag_ab*)&As[(size_t)(wm + im * 16 + fm) * LDK + quad * 8];
#pragma unroll
    for (int in = 0; in < 4; ++in)
      b[in] = *(const frag_ab*)&Bs[(size_t)(wn + in * 16 + fm) * LDK + quad * 8];
#pragma unroll
    for (int im = 0; im < 4; ++im)
#pragma unroll
      for (int in = 0; in < 4; ++in)
        acc[im][in] = __builtin_amdgcn_mfma_f32_16x16x32_bf16(
            a[im], b[in], acc[im][in], 0, 0, 0);
    __syncthreads();
  }
#pragma unroll
  for (int im = 0; im < 4; ++im)
#pragma unroll
    for (int in = 0; in < 4; ++in) {
      const int n = n0 + wn + in * 16 + fm;
#pragma unroll
      for (int r = 0; r < 4; ++r) {
        const int m = m0 + wm + im * 16 + quad * 4 + r;
        C[(size_t)m * Nn + n] = acc[im][in][r];
      }
    }
}

// Fused K/V projection: both 2048x512x2048 GEMMs in one 128-block dispatch.
__global__ __launch_bounds__(256) void gemm_mfma_kv(
    const bfu* __restrict__ A, const bfu* __restrict__ BTk,
    const bfu* __restrict__ BTv, float* __restrict__ Ck, float* __restrict__ Cv,
    int M, int Nn, int K)
{
  constexpr int LDK = 40;
  __shared__ __align__(16) bfu As[128 * LDK];
  __shared__ __align__(16) bfu Bs[128 * LDK];
  const int tid = threadIdx.x;
  int bx = blockIdx.x;
  const bfu* BT; float* C;
  const int nb = Nn / 128;
  if (bx < nb) { BT = BTk; C = Ck; } else { BT = BTv; C = Cv; bx -= nb; }
  const int m0 = blockIdx.y * 128, n0 = bx * 128;
  const int wave = tid >> 6, lane = tid & 63;
  const int wm = (wave >> 1) * 64, wn = (wave & 1) * 64;
  const int fm = lane & 15, quad = lane >> 4;
  const int sr = tid >> 2, skc = (tid & 3) * 8;

  frag_cd acc[4][4];
#pragma unroll
  for (int i = 0; i < 4; ++i)
#pragma unroll
    for (int j = 0; j < 4; ++j) acc[i][j] = (frag_cd){0.f, 0.f, 0.f, 0.f};

  for (int k0 = 0; k0 < K; k0 += 32) {
    *(uint4*)&As[(size_t)sr * LDK + skc] =
        *(const uint4*)(A + (size_t)(m0 + sr) * K + k0 + skc);
    *(uint4*)&As[(size_t)(sr + 64) * LDK + skc] =
        *(const uint4*)(A + (size_t)(m0 + sr + 64) * K + k0 + skc);
    *(uint4*)&Bs[(size_t)sr * LDK + skc] =
        *(const uint4*)(BT + (size_t)(n0 + sr) * K + k0 + skc);
    *(uint4*)&Bs[(size_t)(sr + 64) * LDK + skc] =
        *(const uint4*)(BT + (size_t)(n0 + sr + 64) * K + k0 + skc);
    __syncthreads();
    frag_ab a[4], b[4];
#pragma unroll
    for (int im = 0; im < 4; ++im)
      a[im] = *(const frag_ab*)&As[(size_t)(wm + im * 16 + fm) * LDK + quad * 8];
#pragma unroll
    for (int in = 0; in < 4; ++in)
      b[in] = *(const frag_ab*)&Bs[(size_t)(wn + in * 16 + fm) * LDK + quad * 8];
#pragma unroll
    for (int im = 0; im < 4; ++im)
#pragma unroll
      for (int in = 0; in < 4; ++in)
        acc[im][in] = __builtin_amdgcn_mfma_f32_16x16x32_bf16(
            a[im], b[in], acc[im][in], 0, 0, 0);
    __syncthreads();
  }
#pragma unroll
  for (int im = 0; im < 4; ++im)
#pragma unroll
    for (int in = 0; in < 4; ++in) {
      const int n = n0 + wn + in * 16 + fm;
#pragma unroll
      for (int r = 0; r < 4; ++r) {
        const int m = m0 + wm + im * 16 + quad * 4 + r;
        C[(size_t)m * Nn + n] = acc[im][in][r];
      }
    }
}

// ---------------------------------------------------------------------------
// Per-row (64-wide) softmax of k -> kl, and log_sigmoid(k)/16 -> gl.
// ---------------------------------------------------------------------------
__global__ __launch_bounds__(256) void gates64_k(
    const float* __restrict__ kin, float* __restrict__ kl, float* __restrict__ gl)
{
  const int r = blockIdx.x * 4 + (threadIdx.x >> 6);
  const int lane = threadIdx.x & 63;
  const size_t idx = (size_t)r * 64 + lane;
  const float x = kin[idx];
  float m = x;
#pragma unroll
  for (int o = 32; o > 0; o >>= 1) m = fmaxf(m, __shfl_xor(m, o, 64));
  const float e = __expf(x - m);
  float s = e;
#pragma unroll
  for (int o = 32; o > 0; o >>= 1) s += __shfl_xor(s, o, 64);
  kl[idx] = e / s;
  const float ls = fminf(x, 0.f) - log1pf(__expf(-fabsf(x)));
  gl[idx] = ls * 0.0625f;
}

// ---------------------------------------------------------------------------
// Per (b,hkv,chunk): triangular solves.  256 blocks.
// ---------------------------------------------------------------------------
__global__ __launch_bounds__(256) void chunk_prep_k(
    const float* __restrict__ kl, const float* __restrict__ v,
    const float* __restrict__ gl, float* __restrict__ u_out, float* __restrict__ w_out)
{
  __shared__ float KC[64][65];
  __shared__ float KB[64][65];
  __shared__ float VB[64][65];
  const int blk = blockIdx.x;
  const int c = blk & 15, bh = blk >> 4;
  const int hk = bh & 7, b = bh >> 3;
  const int tid = threadIdx.x;
  for (int x = tid; x < 4096; x += 256) {
    const int i = x >> 6, d = x & 63;
    const size_t src = ((size_t)(b * Nc + c * 64 + i) * 8 + hk) * 64 + d;
    const float kv = kl[src], g = gl[src], vv = v[src];
    KC[i][d] = kv; KB[i][d] = kv * g; VB[i][d] = vv * g;
  }
  __syncthreads();
  float Lreg[16];
#pragma unroll
  for (int e = 0; e < 16; ++e) {
    const int x = e * 256 + tid;
    const int i = x >> 6, j = x & 63;
    float acc = 0.f;
    if (j < i) {
      for (int d = 0; d < 64; ++d) acc += KB[i][d] * KC[j][d];
    }
    Lreg[e] = acc;
  }
  __syncthreads();
#pragma unroll
  for (int e = 0; e < 16; ++e) {
    const int x = e * 256 + tid;
    KC[x >> 6][x & 63] = Lreg[e];
  }
  __syncthreads();
  if (tid < 128) {
    const int d = tid & 63;
    float (*X)[65] = (tid < 64) ? VB : KB;
    for (int i = 1; i < 64; ++i) {
      float acc = X[i][d];
      for (int j = 0; j < i; ++j) acc -= KC[i][j] * X[j][d];
      X[i][d] = acc;
    }
  }
  __syncthreads();
  for (int x = tid; x < 4096; x += 256) {
    u_out[(size_t)blk * 4096 + x] = VB[x >> 6][x & 63];
    w_out[(size_t)blk * 4096 + x] = KB[x >> 6][x & 63];
  }
}

// ---------------------------------------------------------------------------
// Serial scan over chunks per (b,hkv).  16 blocks x 512 threads.
// ---------------------------------------------------------------------------
__global__ __launch_bounds__(512) void scan_k(
    const float* __restrict__ u_ps, const float* __restrict__ w_ps,
    const float* __restrict__ kl, float* __restrict__ u_p, float* __restrict__ S_pre)
{
  __shared__ float S[64][64];
  __shared__ float kw[64][64];
  __shared__ float up[64][72];
  const int blk = blockIdx.x;
  const int hk = blk & 7, b = blk >> 3;
  const int t = threadIdx.x;
  const int row = t >> 3;
  const int c0 = (t & 7) * 8;
  for (int x = t; x < 4096; x += 512) S[x >> 6][x & 63] = 0.f;
  __syncthreads();
  for (int c = 0; c < 16; ++c) {
    const size_t cb = ((size_t)blk * 16 + c) * 4096;
    for (int x = t; x < 4096; x += 512) {
      S_pre[cb + x] = S[x >> 6][x & 63];
      kw[x >> 6][x & 63] = w_ps[cb + x];
    }
    __syncthreads();
    {
      float acc[8];
      const float* ug = u_ps + cb + row * 64 + c0;
#pragma unroll
      for (int j = 0; j < 8; ++j) acc[j] = ug[j];
      for (int e = 0; e < 64; ++e) {
        const float wv = kw[row][e];
#pragma unroll
        for (int j = 0; j < 8; ++j) acc[j] -= wv * S[e][c0 + j];
      }
      float* upg = u_p + cb + row * 64 + c0;
#pragma unroll
      for (int j = 0; j < 8; ++j) { up[row][c0 + j] = acc[j]; upg[j] = acc[j]; }
    }
    __syncthreads();
    for (int x = t; x < 4096; x += 512) {
      const int i = x >> 6, d = x & 63;
      kw[i][d] = kl[((size_t)(b * Nc + c * 64 + i) * 8 + hk) * 64 + d];
    }
    __syncthreads();
    {
      float sacc[8];
#pragma unroll
      for (int j = 0; j < 8; ++j) sacc[j] = S[row][c0 + j];
      for (int i = 0; i < 64; ++i) {
        const float kv = kw[i][row];
#pragma unroll
        for (int j = 0; j < 8; ++j) sacc[j] += kv * up[i][c0 + j];
      }
#pragma unroll
      for (int j = 0; j < 8; ++j) S[row][c0 + j] = sacc[j];
    }
    __syncthreads();
  }
}

// ---------------------------------------------------------------------------
// o_lin per (b,h,chunk).  1024 blocks.
// ---------------------------------------------------------------------------
__global__ __launch_bounds__(256) void olin_k(
    const float* __restrict__ qraw, const float* __restrict__ kl,
    const float* __restrict__ upb, const float* __restrict__ S_pre,
    float* __restrict__ o_comb)
{
  __shared__ float Q[64][65];
  __shared__ __align__(16) float Bb[64][68];
  __shared__ float At[64][65];
  const int blk = blockIdx.x;
  const int c = blk & 15, bh = blk >> 4;
  const int h = bh & 31, b = bh >> 5, hk = h >> 2;
  const int tid = threadIdx.x;
  const int i = tid >> 2, d0 = (tid & 3) * 16;
  for (int x = tid; x < 4096; x += 256) {
    const int r = x >> 6, d = x & 63;
    Q[r][d] = qraw[((size_t)(b * Nc + c * 64 + r) * 32 + h) * 64 + d];
    Bb[r][d] = kl[((size_t)(b * Nc + c * 64 + r) * 8 + hk) * 64 + d];
  }
  __syncthreads();
  {
    float mx = -1e30f;
#pragma unroll
    for (int j = 0; j < 16; ++j) mx = fmaxf(mx, Q[i][d0 + j]);
#pragma unroll
    for (int o = 1; o < 4; o <<= 1) mx = fmaxf(mx, __shfl_xor(mx, o, 64));
    float ev[16];
    float sum = 0.f;
#pragma unroll
    for (int j = 0; j < 16; ++j) { ev[j] = __expf(Q[i][d0 + j] - mx); sum += ev[j]; }
#pragma unroll
    for (int o = 1; o < 4; o <<= 1) sum += __shfl_xor(sum, o, 64);
    const float inv = 1.f / sum;
#pragma unroll
    for (int j = 0; j < 16; ++j) Q[i][d0 + j] = ev[j] * inv;
  }
  {
    float a[16];
#pragma unroll
    for (int j = 0; j < 16; ++j) a[j] = 0.f;
    for (int d = 0; d < 64; ++d) {
      const float qv = Q[i][d];
#pragma unroll
      for (int j = 0; j < 16; ++j) a[j] += qv * Bb[d0 + j][d];
    }
#pragma unroll
    for (int j = 0; j < 16; ++j) At[i][d0 + j] = (d0 + j <= i) ? a[j] : 0.f;
  }
  __syncthreads();
  const size_t cb = ((size_t)(b * 8 + hk) * 16 + c) * 4096;
  for (int x = tid; x < 4096; x += 256) Bb[x >> 6][x & 63] = S_pre[cb + x];
  __syncthreads();
  float o[16];
#pragma unroll
  for (int j = 0; j < 16; ++j) o[j] = 0.f;
  for (int e = 0; e < 64; ++e) {
    const float qv = Q[i][e];
#pragma unroll
    for (int j = 0; j < 16; ++j) o[j] += qv * Bb[e][d0 + j];
  }
  __syncthreads();
  for (int x = tid; x < 4096; x += 256) Bb[x >> 6][x & 63] = upb[cb + x];
  __syncthreads();
  for (int j2 = 0; j2 < 64; ++j2) {
    const float av = At[i][j2];
#pragma unroll
    for (int j = 0; j < 16; ++j) o[j] += av * Bb[j2][d0 + j];
  }
  float* oc = o_comb + ((size_t)(b * Nc + c * 64 + i) * 32 + h) * 64 + d0;
#pragma unroll
  for (int j = 0; j < 16; ++j) oc[j] = 0.5f * o[j];
}

// ---------------------------------------------------------------------------
// Base attention pass A (MFMA): online m,l only, no score writes.
// S^T orientation: A = K (m=j), B = Q (n=i), k = d.  1024 blocks x 256 thr.
// ---------------------------------------------------------------------------
__global__ __launch_bounds__(256) void ml_mfma_k(
    const float* __restrict__ qraw, const float* __restrict__ kraw,
    float* __restrict__ mbuf, float* __restrict__ lbuf)
{
  constexpr int LDK = 72;
  __shared__ __align__(16) bfu Qt[64 * LDK];  // [i][d]
  __shared__ __align__(16) bfu Kt[64 * LDK];  // [j][d]
  __shared__ float mred[4][64];
  __shared__ float lred[4][64];
  const int blk = blockIdx.x;
  const int ib = blk & 15, bh = blk >> 4;
  const int h = bh & 31, b = bh >> 5, hk = h >> 2;
  const int tid = threadIdx.x;
  const int wave = tid >> 6, lane = tid & 63;
  const int fm = lane & 15, quad = lane >> 4;
  const int wj = wave * 16;
  const int srow = tid >> 2, sd0 = (tid & 3) * 16;

  // stage Qt [i][d] bf16
  {
    const float* qp = qraw + ((size_t)(b * Nc + ib * 64 + srow) * 32 + h) * 64 + sd0;
    bfu* dst = &Qt[(size_t)srow * LDK + sd0];
#pragma unroll
    for (int e = 0; e < 4; ++e)
      *(ushort4*)(dst + e * 4) = pack4(*(const float4*)(qp + e * 4));
  }
  __syncthreads();
  // Q B-frags: [n = in*16+fm][k = kk*32 + quad*8], loaded once
  frag_ab qb[4][2];
#pragma unroll
  for (int in = 0; in < 4; ++in)
#pragma unroll
    for (int kk = 0; kk < 2; ++kk)
      qb[in][kk] = *(const frag_ab*)&Qt[(size_t)(in * 16 + fm) * LDK + kk * 32 + quad * 8];

  float m[4], l[4];
#pragma unroll
  for (int in = 0; in < 4; ++in) { m[in] = -1e30f; l[in] = 0.f; }

  for (int jt = 0; jt <= ib; ++jt) {
    __syncthreads();
    {
      const float* kp = kraw + ((size_t)(b * Nc + jt * 64 + srow) * 8 + hk) * 64 + sd0;
      bfu* dst = &Kt[(size_t)srow * LDK + sd0];
#pragma unroll
      for (int e = 0; e < 4; ++e)
        *(ushort4*)(dst + e * 4) = pack4(*(const float4*)(kp + e * 4));
    }
    __syncthreads();
    frag_ab ka[2];
    ka[0] = *(const frag_ab*)&Kt[(size_t)(wj + fm) * LDK + quad * 8];
    ka[1] = *(const frag_ab*)&Kt[(size_t)(wj + fm) * LDK + 32 + quad * 8];
    const bool diag = (jt == ib);
#pragma unroll
    for (int in = 0; in < 4; ++in) {
      frag_cd acc = (frag_cd){0.f, 0.f, 0.f, 0.f};
      acc = __builtin_amdgcn_mfma_f32_16x16x32_bf16(ka[0], qb[in][0], acc, 0, 0, 0);
      acc = __builtin_amdgcn_mfma_f32_16x16x32_bf16(ka[1], qb[in][1], acc, 0, 0, 0);
      // lane holds S^T[j = wj+quad*4+r][i = in*16+fm]
      const int iloc = in * 16 + fm;
      float sv[4];
      bool vd[4];
      float tm = -1e30f;
#pragma unroll
      for (int r = 0; r < 4; ++r) {
        const int jloc = wj + quad * 4 + r;
        vd[r] = !diag || (jloc <= iloc);
        sv[r] = acc[r] * 0.125f;
        if (vd[r]) tm = fmaxf(tm, sv[r]);
      }
      const float mn = fmaxf(m[in], tm);
      float lsum = 0.f;
#pragma unroll
      for (int r = 0; r < 4; ++r)
        if (vd[r]) lsum += __expf(sv[r] - mn);
      l[in] = l[in] * __expf(m[in] - mn) + lsum;  // l==0 when m==-1e30, safe
      m[in] = mn;
    }
  }
  // reduce across quads (lanes fm fixed, quad varies): offsets 16, 32
#pragma unroll
  for (int in = 0; in < 4; ++in) {
    float mm = m[in], ll = l[in];
#pragma unroll
    for (int off = 16; off < 64; off <<= 1) {
      const float mo = __shfl_xor(mm, off, 64);
      const float lo = __shfl_xor(ll, off, 64);
      const float mn = fmaxf(mm, mo);
      ll = ll * __expf(mm - mn) + lo * __expf(mo - mn);
      mm = mn;
    }
    if (quad == 0) { mred[wave][in * 16 + fm] = mm; lred[wave][in * 16 + fm] = ll; }
  }
  __syncthreads();
  if (tid < 64) {
    float M = -1e30f;
#pragma unroll
    for (int w = 0; w < 4; ++w) M = fmaxf(M, mred[w][tid]);
    float L = 0.f;
#pragma unroll
    for (int w = 0; w < 4; ++w) L += lred[w][tid] * __expf(mred[w][tid] - M);
    const size_t rowi = (size_t)(b * 32 + h) * 1024 + ib * 64 + tid;
    mbuf[rowi] = M;
    lbuf[rowi] = L;
  }
}

// ---------------------------------------------------------------------------
// Base attention pass B (MFMA): recompute scores, p = exp(s-m)/l -> attn
// (fp32, zero above diagonal), PV via MFMA (P staged bf16, V^T staged bf16),
// o_comb += 0.5 * o.  1024 blocks x 256 threads.
// ---------------------------------------------------------------------------
__global__ __launch_bounds__(256) void pv_mfma_k(
    const float* __restrict__ qraw, const float* __restrict__ kraw,
    const float* __restrict__ vraw, const float* __restrict__ mbuf,
    const float* __restrict__ lbuf, float* __restrict__ attn,
    float* __restrict__ o_comb)
{
  constexpr int LDK = 72;
  __shared__ __align__(16) bfu Qt[64 * LDK];    // [i][d]
  __shared__ __align__(16) bfu Kt[64 * LDK];    // [j][d]
  __shared__ __align__(16) bfu Vt[64 * LDK];    // [dv][j]  (transposed)
  __shared__ __align__(16) bfu Pmat[64 * LDK];  // [i][j]
  const int blk = blockIdx.x;
  const int ib = blk & 15, bh = blk >> 4;
  const int h = bh & 31, b = bh >> 5, hk = h >> 2;
  const int tid = threadIdx.x;
  const int wave = tid >> 6, lane = tid & 63;
  const int fm = lane & 15, quad = lane >> 4;
  const int wj = wave * 16;   // score phase: wave's j slice
  const int im0 = wave * 16;  // PV phase: wave's i slice
  const int srow = tid >> 2, sd0 = (tid & 3) * 16;

  // stage Qt
  {
    const float* qp = qraw + ((size_t)(b * Nc + ib * 64 + srow) * 32 + h) * 64 + sd0;
    bfu* dst = &Qt[(size_t)srow * LDK + sd0];
#pragma unroll
    for (int e = 0; e < 4; ++e)
      *(ushort4*)(dst + e * 4) = pack4(*(const float4*)(qp + e * 4));
  }
  __syncthreads();
  frag_ab qb[4][2];
#pragma unroll
  for (int in = 0; in < 4; ++in)
#pragma unroll
    for (int kk = 0; kk < 2; ++kk)
      qb[in][kk] = *(const frag_ab*)&Qt[(size_t)(in * 16 + fm) * LDK + kk * 32 + quad * 8];

  // per-lane m, 1/l for its 4 i's (i = in*16+fm), constant across jt
  float mi[4], il[4];
#pragma unroll
  for (int in = 0; in < 4; ++in) {
    const size_t rowi = (size_t)(b * 32 + h) * 1024 + ib * 64 + in * 16 + fm;
    mi[in] = mbuf[rowi];
    il[in] = 1.f / lbuf[rowi];
  }

  float* arow0 = attn + ((size_t)(b * 32 + h) * 1024 + ib * 64) * 1024;

  frag_cd o[4];
#pragma unroll
  for (int in = 0; in < 4; ++in) o[in] = (frag_cd){0.f, 0.f, 0.f, 0.f};

  for (int jt = 0; jt <= ib; ++jt) {
    __syncthreads();  // protect prev iter's Vt/Pmat reads
    // stage Kt [j][d]
    {
      const float* kp = kraw + ((size_t)(b * Nc + jt * 64 + srow) * 8 + hk) * 64 + sd0;
      bfu* dst = &Kt[(size_t)srow * LDK + sd0];
#pragma unroll
      for (int e = 0; e < 4; ++e)
        *(ushort4*)(dst + e * 4) = pack4(*(const float4*)(kp + e * 4));
    }
    // stage Vt [dv][j] via register 4x4 transpose
    {
      const int jg = (tid & 15) * 4, dvg = (tid >> 4) * 4;
      float4 rv[4];
#pragma unroll
      for (int rr = 0; rr < 4; ++rr)
        rv[rr] = *(const float4*)(vraw + ((size_t)(b * Nc + jt * 64 + jg + rr) * 8 + hk) * 64 + dvg);
#pragma unroll
      for (int e = 0; e < 4; ++e) {
        ushort4 w;
        w.x = f2bf(((const float*)&rv[0])[e]);
        w.y = f2bf(((const float*)&rv[1])[e]);
        w.z = f2bf(((const float*)&rv[2])[e]);
        w.w = f2bf(((const float*)&rv[3])[e]);
        *(ushort4*)&Vt[(size_t)(dvg + e) * LDK + jg] = w;
      }
    }
    __syncthreads();
    // scores S^T: A = K rows (wave's j slice), B = Q
    frag_ab ka[2];
    ka[0] = *(const frag_ab*)&Kt[(size_t)(wj + fm) * LDK + quad * 8];
    ka[1] = *(const frag_ab*)&Kt[(size_t)(wj + fm) * LDK + 32 + quad * 8];
    const bool diag = (jt == ib);
#pragma unroll
    for (int in = 0; in < 4; ++in) {
      frag_cd acc = (frag_cd){0.f, 0.f, 0.f, 0.f};
      acc = __builtin_amdgcn_mfma_f32_16x16x32_bf16(ka[0], qb[in][0], acc, 0, 0, 0);
      acc = __builtin_amdgcn_mfma_f32_16x16x32_bf16(ka[1], qb[in][1], acc, 0, 0, 0);
      const int iloc = in * 16 + fm;
      float p[4];
#pragma unroll
      for (int r = 0; r < 4; ++r) {
        const int jloc = wj + quad * 4 + r;
        const bool vdr = !diag || (jloc <= iloc);
        p[r] = vdr ? __expf(acc[r] * 0.125f - mi[in]) * il[in] : 0.f;
      }
      // write p to attn: row iloc, 4 consecutive cols jt*64 + wj + quad*4
      *(float4*)(arow0 + (size_t)iloc * 1024 + jt * 64 + wj + quad * 4) =
          make_float4(p[0], p[1], p[2], p[3]);
      // stage p into Pmat [i][j] bf16
      ushort4 w;
      w.x = f2bf(p[0]); w.y = f2bf(p[1]); w.z = f2bf(p[2]); w.w = f2bf(p[3]);
      *(ushort4*)&Pmat[(size_t)iloc * LDK + wj + quad * 4] = w;
    }
    __syncthreads();
    // PV: A = Pmat rows (wave's i slice), B = Vt rows (dv), k = j
    frag_ab pa[2];
    pa[0] = *(const frag_ab*)&Pmat[(size_t)(im0 + fm) * LDK + quad * 8];
    pa[1] = *(const frag_ab*)&Pmat[(size_t)(im0 + fm) * LDK + 32 + quad * 8];
#pragma unroll
    for (int in = 0; in < 4; ++in) {
      frag_ab vb0 = *(const frag_ab*)&Vt[(size_t)(in * 16 + fm) * LDK + quad * 8];
      frag_ab vb1 = *(const frag_ab*)&Vt[(size_t)(in * 16 + fm) * LDK + 32 + quad * 8];
      o[in] = __builtin_amdgcn_mfma_f32_16x16x32_bf16(pa[0], vb0, o[in], 0, 0, 0);
      o[in] = __builtin_amdgcn_mfma_f32_16x16x32_bf16(pa[1], vb1, o[in], 0, 0, 0);
    }
  }
  // zero-fill non-causal tiles of attn
  for (int jt2 = ib + 1; jt2 < 16; ++jt2) {
    const float4 z = make_float4(0.f, 0.f, 0.f, 0.f);
    for (int x = tid; x < 1024; x += 256) {
      const int row = x >> 4, c4 = (x & 15) * 4;
      *(float4*)(arow0 + (size_t)row * 1024 + jt2 * 64 + c4) = z;
    }
  }
  // o_comb += 0.5 * o   (o: row i = im0+quad*4+r, col dv = in*16+fm)
#pragma unroll
  for (int in = 0; in < 4; ++in)
#pragma unroll
    for (int r = 0; r < 4; ++r) {
      const int i = im0 + quad * 4 + r;
      float* oc = o_comb + ((size_t)(b * Nc + ib * 64 + i) * 32 + h) * 64 + in * 16 + fm;
      *oc += 0.5f * o[in][r];
    }
}

// ---------------------------------------------------------------------------
extern "C" void kernel_launch(void* const* d_in, const int* in_sizes, int n_in,
                              void* d_out, int out_size, void* d_ws, size_t ws_size,
                              hipStream_t stream) {
  const float* hs = (const float*)d_in[0];
  const float* Wq = (const float*)d_in[1];
  const float* Wk = (const float*)d_in[2];
  const float* Wv = (const float*)d_in[3];
  const float* Wo = (const float*)d_in[4];
  float* out = (float*)d_out;                      // [B,N,HID]
  float* attn = out + (size_t)Bc * Nc * HIDc;      // [B,H,N,N]

  float* ws = (float*)d_ws;
  float* q_raw  = ws;                     // 4,194,304 f32
  float* k_raw  = q_raw + 4194304;        // 1,048,576
  float* v_raw  = k_raw + 1048576;        // 1,048,576
  float* kl     = v_raw + 1048576;        // 1,048,576
  float* gl     = kl + 1048576;           // 1,048,576
  float* u_ps   = gl + 1048576;           // 2,097,152
  float* w_ps   = u_ps + 2097152;         // 2,097,152
  float* upb    = w_ps + 2097152;         // 2,097,152
  float* S_pre  = upb + 2097152;          // 2,097,152
  float* o_comb = S_pre + 2097152;        // 4,194,304
  float* mbuf   = o_comb + 4194304;       // 65,536
  float* lbuf   = mbuf + 65536;           // 65,536
  bfu* bstart = (bfu*)(lbuf + 65536);
  bfu* hs_bf  = bstart;                   // 4,194,304 bf16
  bfu* WqT    = hs_bf + 4194304;          // 4,194,304
  bfu* WkT    = WqT + 4194304;            // 1,048,576
  bfu* WvT    = WkT + 1048576;            // 1,048,576
  bfu* WoT    = WvT + 1048576;            // 4,194,304
  bfu* oc_bf  = WoT + 4194304;            // 4,194,304

  // Casts / weight transposes
  cast_bf16_k<<<4096, 256, 0, stream>>>(hs, hs_bf);
  transpose_cast_k<<<dim3(64, 64), 256, 0, stream>>>(Wq, WqT, 2048, 2048);
  transpose_cast_k<<<dim3(16, 64), 256, 0, stream>>>(Wk, WkT, 2048, 512);
  transpose_cast_k<<<dim3(16, 64), 256, 0, stream>>>(Wv, WvT, 2048, 512);
  transpose_cast_k<<<dim3(64, 64), 256, 0, stream>>>(Wo, WoT, 2048, 2048);
  // Projections (bf16 MFMA)
  gemm_mfma_bt<<<dim3(16, 16), 256, 0, stream>>>(hs_bf, WqT, q_raw, 2048, 2048, 2048);
  gemm_mfma_kv<<<dim3(8, 16), 256, 0, stream>>>(hs_bf, WkT, WvT, k_raw, v_raw, 2048, 512, 2048);
  // Gates / feature maps
  gates64_k<<<4096, 256, 0, stream>>>(k_raw, kl, gl);
  // Delta-rule
  chunk_prep_k<<<256, 256, 0, stream>>>(kl, v_raw, gl, u_ps, w_ps);
  scan_k<<<16, 512, 0, stream>>>(u_ps, w_ps, kl, upb, S_pre);
  // Linear-attention output (writes o_comb = 0.5*o_lin)
  olin_k<<<1024, 256, 0, stream>>>(q_raw, kl, upb, S_pre, o_comb);
  // Base causal attention: MFMA m,l pass then fused p/attn-write/PV pass
  ml_mfma_k<<<1024, 256, 0, stream>>>(q_raw, k_raw, mbuf, lbuf);
  pv_mfma_k<<<1024, 256, 0, stream>>>(q_raw, k_raw, v_raw, mbuf, lbuf, attn, o_comb);
  // Output projection
  cast_bf16_k<<<4096, 256, 0, stream>>>(o_comb, oc_bf);
  gemm_mfma_bt<<<dim3(16, 16), 256, 0, stream>>>(oc_bf, WoT, out, 2048, 2048, 2048);
}